// Round 1
// baseline (4448.207 us; speedup 1.0000x reference)
//
#include <hip/hip_runtime.h>

#define HID 128
#define NG 64

__device__ __forceinline__ float lrelu(float v) { return v > 0.0f ? v : 0.2f * v; }

// order-preserving float->uint encoding for atomicMax
__device__ __forceinline__ unsigned int encf(float v) {
    unsigned int u = __float_as_uint(v);
    return (u & 0x80000000u) ? ~u : (u | 0x80000000u);
}
__device__ __forceinline__ float decf(unsigned int e) {
    unsigned int u = (e & 0x80000000u) ? (e ^ 0x80000000u) : ~e;
    return __uint_as_float(u);
}

// ---------------- layer 1 node transform: h = x @ W1 ; a_s, a_d ----------------
__global__ __launch_bounds__(128) void k_node1(const float* __restrict__ x,
        const float* __restrict__ W, const float* __restrict__ asW, const float* __restrict__ adW,
        float* __restrict__ h, float* __restrict__ as_, float* __restrict__ ad_, int N)
{
    __shared__ float Wl[16 * 128];
    __shared__ float xs[16];
    int t = threadIdx.x;
    for (int i = t; i < 16 * 128; i += 128) Wl[i] = W[i];
    float av_s = asW[t], av_d = adW[t];
    __syncthreads();
    for (int n = blockIdx.x; n < N; n += gridDim.x) {
        if (t < 16) xs[t] = x[n * 16 + t];
        __syncthreads();
        float acc = 0.f;
#pragma unroll
        for (int k = 0; k < 16; ++k) acc = fmaf(xs[k], Wl[k * 128 + t], acc);
        h[n * 128 + t] = acc;
        float ps = acc * av_s, pd = acc * av_d;
#pragma unroll
        for (int off = 16; off; off >>= 1) { ps += __shfl_xor(ps, off); pd += __shfl_xor(pd, off); }
        if ((t & 31) == 0) { int hd = t >> 5; as_[n * 4 + hd] = ps; ad_[n * 4 + hd] = pd; }
        __syncthreads();
    }
}

// ---------------- edge pass 1: segment max ----------------
__global__ __launch_bounds__(256) void k_edge_max(const int* __restrict__ ei,
        const float* __restrict__ as_, const float* __restrict__ ad_,
        unsigned int* __restrict__ m, int E)
{
    int i = blockIdx.x * blockDim.x + threadIdx.x;
    int stride = gridDim.x * blockDim.x;
    for (int e = i; e < E; e += stride) {
        int s = ei[e], d = ei[E + e];
        const float4 a = *(const float4*)(as_ + (size_t)s * 4);
        const float4 b = *(const float4*)(ad_ + (size_t)d * 4);
        float eh[4] = {a.x + b.x, a.y + b.y, a.z + b.z, a.w + b.w};
#pragma unroll
        for (int hd = 0; hd < 4; ++hd) {
            atomicMax(&m[d * 4 + hd], encf(lrelu(eh[hd])));
        }
    }
}

// ---------------- edge pass 2: segment sum of exp ----------------
__global__ __launch_bounds__(256) void k_edge_sum(const int* __restrict__ ei,
        const float* __restrict__ as_, const float* __restrict__ ad_,
        const unsigned int* __restrict__ m, float* __restrict__ sArr, int E)
{
    int i = blockIdx.x * blockDim.x + threadIdx.x;
    int stride = gridDim.x * blockDim.x;
    for (int e = i; e < E; e += stride) {
        int s = ei[e], d = ei[E + e];
        const float4 a = *(const float4*)(as_ + (size_t)s * 4);
        const float4 b = *(const float4*)(ad_ + (size_t)d * 4);
        float eh[4] = {a.x + b.x, a.y + b.y, a.z + b.z, a.w + b.w};
#pragma unroll
        for (int hd = 0; hd < 4; ++hd) {
            float v = lrelu(eh[hd]);
            float w = __expf(v - decf(m[d * 4 + hd]));
            atomicAdd(&sArr[d * 4 + hd], w);
        }
    }
}

// ---------------- edge pass 3: weighted aggregation ----------------
__global__ __launch_bounds__(256) void k_edge_agg(const int* __restrict__ ei,
        const float* __restrict__ as_, const float* __restrict__ ad_,
        const unsigned int* __restrict__ m, const float* __restrict__ sArr,
        const float* __restrict__ h, float* __restrict__ out, int E)
{
    int i = blockIdx.x * blockDim.x + threadIdx.x;
    int stride = gridDim.x * blockDim.x;
    int total = E * 128;
    for (; i < total; i += stride) {
        int e = i >> 7, c = i & 127;
        int s = ei[e], d = ei[E + e];
        int hd = c >> 5;
        float av = as_[s * 4 + hd] + ad_[d * 4 + hd];
        float v = lrelu(av);
        float w = __expf(v - decf(m[d * 4 + hd]));
        float alpha = w / (sArr[d * 4 + hd] + 1e-16f);
        atomicAdd(&out[(size_t)d * 128 + c], h[(size_t)s * 128 + c] * alpha);
    }
}

// ---------------- BN stats (per channel over N rows) ----------------
__global__ __launch_bounds__(256) void k_bnstats(const float* __restrict__ x,
        double* __restrict__ sums, int N)
{
    int c = threadIdx.x & 127;
    int n = blockIdx.x * 2 + (threadIdx.x >> 7);
    int rstride = gridDim.x * 2;
    float s1 = 0.f, s2 = 0.f;
    for (; n < N; n += rstride) { float v = x[(size_t)n * 128 + c]; s1 += v; s2 += v * v; }
    atomicAdd(&sums[c], (double)s1);
    atomicAdd(&sums[128 + c], (double)s2);
}

__global__ __launch_bounds__(128) void k_bnscale(const double* __restrict__ sums,
        const float* __restrict__ gamma, const float* __restrict__ beta,
        float* __restrict__ scale, float* __restrict__ shift, int N)
{
    int c = threadIdx.x;
    double mu = sums[c] / (double)N;
    double var = sums[128 + c] / (double)N - mu * mu;
    if (var < 0.0) var = 0.0;
    double rs = 1.0 / sqrt(var + 1e-5);
    float sc = (float)((double)gamma[c] * rs);
    scale[c] = sc;
    shift[c] = beta[c] - (float)mu * sc;
}

// ---------------- layer 2 node transform: h2 = relu(bn(out1)) @ W2 ; a_s2, a_d2 ----------------
__global__ __launch_bounds__(128) void k_node2(const float* __restrict__ xin,
        const float* __restrict__ W, const float* __restrict__ scale, const float* __restrict__ shift,
        const float* __restrict__ asW, const float* __restrict__ adW,
        float* __restrict__ h, float* __restrict__ as_, float* __restrict__ ad_, int N)
{
    __shared__ float4 xs4[128];
    int t = threadIdx.x;
    float wreg[128];
#pragma unroll
    for (int k = 0; k < 128; ++k) wreg[k] = W[k * 128 + t];
    float sc = scale[t], sh = shift[t];
    float av_s = asW[t], av_d = adW[t];
    for (int n0 = blockIdx.x * 4; n0 < N; n0 += gridDim.x * 4) {
        float4 col;
        float* cf = (float*)&col;
#pragma unroll
        for (int j = 0; j < 4; ++j) {
            float v = 0.f;
            if (n0 + j < N) {
                v = fmaf(xin[(size_t)(n0 + j) * 128 + t], sc, sh);
                v = v > 0.f ? v : 0.f;
            }
            cf[j] = v;
        }
        __syncthreads();
        xs4[t] = col;
        __syncthreads();
        float a0 = 0.f, a1 = 0.f, a2 = 0.f, a3 = 0.f;
#pragma unroll
        for (int k = 0; k < 128; ++k) {
            float4 xv = xs4[k];
            float w = wreg[k];
            a0 = fmaf(xv.x, w, a0);
            a1 = fmaf(xv.y, w, a1);
            a2 = fmaf(xv.z, w, a2);
            a3 = fmaf(xv.w, w, a3);
        }
        float accs[4] = {a0, a1, a2, a3};
#pragma unroll
        for (int j = 0; j < 4; ++j) {
            if (n0 + j >= N) break;
            float acc = accs[j];
            h[(size_t)(n0 + j) * 128 + t] = acc;
            float ps = acc * av_s, pd = acc * av_d;
#pragma unroll
            for (int off = 16; off; off >>= 1) { ps += __shfl_xor(ps, off); pd += __shfl_xor(pd, off); }
            if ((t & 31) == 0) { int hd = t >> 5; as_[(n0 + j) * 4 + hd] = ps; ad_[(n0 + j) * 4 + hd] = pd; }
        }
    }
}

// ---------------- pool: per-graph sums with run-length local accumulation ----------------
__global__ __launch_bounds__(128) void k_pool(const float* __restrict__ x,
        const int* __restrict__ batch, const float* __restrict__ scale, const float* __restrict__ shift,
        float* __restrict__ gsum, float* __restrict__ gcnt, int N)
{
    int c = threadIdx.x;
    int n0 = blockIdx.x * 64;
    if (n0 >= N) return;
    int n1 = n0 + 64; if (n1 > N) n1 = N;
    float sc = scale[c], sh = shift[c];
    float acc = 0.f; int cnt = 0; int cur = batch[n0];
    for (int n = n0; n < n1; ++n) {
        int g = batch[n];
        if (g != cur) {
            atomicAdd(&gsum[cur * 128 + c], acc);
            if (c == 0) atomicAdd(&gcnt[cur], (float)cnt);
            acc = 0.f; cnt = 0; cur = g;
        }
        float v = fmaf(x[(size_t)n * 128 + c], sc, sh);
        acc += (v > 0.f ? v : 0.f);
        cnt++;
    }
    atomicAdd(&gsum[cur * 128 + c], acc);
    if (c == 0) atomicAdd(&gcnt[cur], (float)cnt);
}

// ---------------- dense head (single block) ----------------
__global__ __launch_bounds__(256) void k_head(const float* __restrict__ gsum, const float* __restrict__ gcnt,
        const float* __restrict__ d1W, const float* __restrict__ d1b,
        const float* __restrict__ g_d1, const float* __restrict__ b_d1,
        const float* __restrict__ d2W, const float* __restrict__ d2b,
        const float* __restrict__ g_d2, const float* __restrict__ b_d2,
        const float* __restrict__ fcW, const float* __restrict__ fcb,
        float* __restrict__ out)
{
    __shared__ float G[64 * 128];
    __shared__ float Y1[64 * 64];
    __shared__ float Y2[64 * 32];
    int t = threadIdx.x;
    for (int i = t; i < 64 * 128; i += 256) {
        int g = i >> 7;
        float cv = gcnt[g]; if (cv < 1.f) cv = 1.f;
        G[i] = gsum[i] / cv;
    }
    __syncthreads();
    // d1: 64x64, K=128
    for (int i = t; i < 64 * 64; i += 256) {
        int r = i >> 6, j = i & 63;
        float a = 0.f;
        for (int k = 0; k < 128; ++k) a = fmaf(G[r * 128 + k], d1W[k * 64 + j], a);
        Y1[i] = a + d1b[j];
    }
    __syncthreads();
    if (t < 64) {
        float s1 = 0.f, s2 = 0.f;
        for (int r = 0; r < 64; ++r) { float v = Y1[r * 64 + t]; s1 += v; s2 += v * v; }
        float mu = s1 / 64.f, var = s2 / 64.f - mu * mu; if (var < 0.f) var = 0.f;
        float rs = 1.0f / sqrtf(var + 1e-5f);
        float scv = g_d1[t] * rs, shv = b_d1[t] - mu * scv;
        for (int r = 0; r < 64; ++r) {
            float v = fmaf(Y1[r * 64 + t], scv, shv);
            Y1[r * 64 + t] = v > 0.f ? v : 0.f;
        }
    }
    __syncthreads();
    // d2: 64x32, K=64
    for (int i = t; i < 64 * 32; i += 256) {
        int r = i >> 5, j = i & 31;
        float a = 0.f;
        for (int k = 0; k < 64; ++k) a = fmaf(Y1[r * 64 + k], d2W[k * 32 + j], a);
        Y2[i] = a + d2b[j];
    }
    __syncthreads();
    if (t < 32) {
        float s1 = 0.f, s2 = 0.f;
        for (int r = 0; r < 64; ++r) { float v = Y2[r * 32 + t]; s1 += v; s2 += v * v; }
        float mu = s1 / 64.f, var = s2 / 64.f - mu * mu; if (var < 0.f) var = 0.f;
        float rs = 1.0f / sqrtf(var + 1e-5f);
        float scv = g_d2[t] * rs, shv = b_d2[t] - mu * scv;
        for (int r = 0; r < 64; ++r) {
            float v = fmaf(Y2[r * 32 + t], scv, shv);
            Y2[r * 32 + t] = v > 0.f ? v : 0.f;
        }
    }
    __syncthreads();
    // fc: 64x4, K=32
    if (t < 256) {
        int r = t >> 2, j = t & 3;
        float a = 0.f;
        for (int k = 0; k < 32; ++k) a = fmaf(Y2[r * 32 + k], fcW[k * 4 + j], a);
        out[t] = a + fcb[j];
    }
}

extern "C" void kernel_launch(void* const* d_in, const int* in_sizes, int n_in,
                              void* d_out, int out_size, void* d_ws, size_t ws_size,
                              hipStream_t stream) {
    const int N = in_sizes[0] / 16;
    const int E = in_sizes[1] / 2;

    const float* x        = (const float*)d_in[0];
    const int*   ei       = (const int*)d_in[1];
    const int*   batch    = (const int*)d_in[2];
    const float* W1       = (const float*)d_in[3];
    const float* att_s1   = (const float*)d_in[5];
    const float* att_d1   = (const float*)d_in[6];
    const float* bn_g1    = (const float*)d_in[7];
    const float* bn_b1    = (const float*)d_in[8];
    const float* W2       = (const float*)d_in[9];
    const float* att_s2   = (const float*)d_in[11];
    const float* att_d2   = (const float*)d_in[12];
    const float* bn_g2    = (const float*)d_in[13];
    const float* bn_b2    = (const float*)d_in[14];
    const float* d1W      = (const float*)d_in[15];
    const float* d1b      = (const float*)d_in[16];
    const float* g_d1     = (const float*)d_in[17];
    const float* b_d1     = (const float*)d_in[18];
    const float* d2W      = (const float*)d_in[19];
    const float* d2b      = (const float*)d_in[20];
    const float* g_d2     = (const float*)d_in[21];
    const float* b_d2     = (const float*)d_in[22];
    const float* fcW      = (const float*)d_in[23];
    const float* fcb      = (const float*)d_in[24];
    float* out = (float*)d_out;

    float* ws = (float*)d_ws;
    size_t o = 0;
    float* hbuf = ws + o;              o += (size_t)N * 128;
    float* as_  = ws + o;              o += (size_t)N * 4;
    float* ad_  = ws + o;              o += (size_t)N * 4;
    float* scale1 = ws + o;            o += 128;
    float* shift1 = ws + o;            o += 128;
    float* scale2 = ws + o;            o += 128;
    float* shift2 = ws + o;            o += 128;
    // zero-region starts here (contiguous): outb, m, sArr, bnsum, gsum, gcnt
    float* outb = ws + o;              size_t zoff = o; o += (size_t)N * 128;
    unsigned int* m = (unsigned int*)(ws + o); o += (size_t)N * 4;
    float* sArr = ws + o;              o += (size_t)N * 4;
    double* bnsum = (double*)(ws + o); o += 512;  // 256 doubles
    float* gsum = ws + o;              o += 64 * 128;
    float* gcnt = ws + o;              o += 64;
    size_t zbytes = (o - zoff) * 4;

    // zero: out1 accumulator + m + s + bnsum + gsum + gcnt
    hipMemsetAsync(ws + zoff, 0, zbytes, stream);

    // ---- layer 1 ----
    k_node1<<<2048, 128, 0, stream>>>(x, W1, att_s1, att_d1, hbuf, as_, ad_, N);
    k_edge_max<<<2048, 256, 0, stream>>>(ei, as_, ad_, m, E);
    k_edge_sum<<<2048, 256, 0, stream>>>(ei, as_, ad_, m, sArr, E);
    k_edge_agg<<<8192, 256, 0, stream>>>(ei, as_, ad_, m, sArr, hbuf, outb, E);
    k_bnstats<<<2048, 256, 0, stream>>>(outb, bnsum, N);
    k_bnscale<<<1, 128, 0, stream>>>(bnsum, bn_g1, bn_b1, scale1, shift1, N);

    // re-zero m, s, bnsum for layer 2 (contiguous region)
    {
        size_t z2 = ((size_t)N * 4 + (size_t)N * 4 + 512) * 4;
        hipMemsetAsync((void*)m, 0, z2, stream);
    }

    // ---- layer 2 ----
    k_node2<<<2048, 128, 0, stream>>>(outb, W2, scale1, shift1, att_s2, att_d2, hbuf, as_, ad_, N);
    hipMemsetAsync((void*)outb, 0, (size_t)N * 128 * 4, stream);
    k_edge_max<<<2048, 256, 0, stream>>>(ei, as_, ad_, m, E);
    k_edge_sum<<<2048, 256, 0, stream>>>(ei, as_, ad_, m, sArr, E);
    k_edge_agg<<<8192, 256, 0, stream>>>(ei, as_, ad_, m, sArr, hbuf, outb, E);
    k_bnstats<<<2048, 256, 0, stream>>>(outb, bnsum, N);
    k_bnscale<<<1, 128, 0, stream>>>(bnsum, bn_g2, bn_b2, scale2, shift2, N);

    // ---- pool + head ----
    k_pool<<<(N + 63) / 64, 128, 0, stream>>>(outb, batch, scale2, shift2, gsum, gcnt, N);
    k_head<<<1, 256, 0, stream>>>(gsum, gcnt, d1W, d1b, g_d1, b_d1,
                                  d2W, d2b, g_d2, b_d2, fcW, fcb, out);
}

// Round 2
// 1714.724 us; speedup vs baseline: 2.5941x; 2.5941x over previous
//
#include <hip/hip_runtime.h>

#define HID 128
#define NG 64

__device__ __forceinline__ float lrelu(float v) { return v > 0.0f ? v : 0.2f * v; }

// ================= unified node-transform GEMM =================
// h[n][c] = sum_k act(xin[n][k]) * W[k][c];  also a_s[n][hd], a_d[n][hd]
// act = BN(scale,shift)+relu when BN==true, identity otherwise.
// Block: 256 threads. Tile: 64 nodes x 128 channels.
// Thread (cq = t&31, nr = t>>5): nodes nr*8..nr*8+7, channels cq*4..cq*4+3.
template <int K, bool BN>
__global__ __launch_bounds__(256) void k_gemm(const float* __restrict__ xin,
        const float* __restrict__ W,
        const float* __restrict__ scale, const float* __restrict__ shift,
        const float* __restrict__ attS, const float* __restrict__ attD,
        float* __restrict__ h, float* __restrict__ as_, float* __restrict__ ad_, int N)
{
    __shared__ float xs[64][K];
    constexpr int K4 = K / 4;
    int t = threadIdx.x;
    int cq = t & 31;
    int nr = t >> 5;

    float4 atS = ((const float4*)attS)[cq];
    float4 atD = ((const float4*)attD)[cq];

    for (int n0 = blockIdx.x * 64; n0 < N; n0 += gridDim.x * 64) {
        int nrem = N - n0; if (nrem > 64) nrem = 64;
        // ---- stage x tile (apply BN+relu if requested) ----
        for (int idx = t; idx < 64 * K4; idx += 256) {
            int n = idx / K4, k4 = idx % K4;
            float4 v = make_float4(0.f, 0.f, 0.f, 0.f);
            if (n < nrem) {
                v = ((const float4*)(xin + (size_t)(n0 + n) * K))[k4];
                if (BN) {
                    float4 sc = ((const float4*)scale)[k4];
                    float4 sh = ((const float4*)shift)[k4];
                    v.x = fmaf(v.x, sc.x, sh.x); v.x = v.x > 0.f ? v.x : 0.f;
                    v.y = fmaf(v.y, sc.y, sh.y); v.y = v.y > 0.f ? v.y : 0.f;
                    v.z = fmaf(v.z, sc.z, sh.z); v.z = v.z > 0.f ? v.z : 0.f;
                    v.w = fmaf(v.w, sc.w, sh.w); v.w = v.w > 0.f ? v.w : 0.f;
                }
            }
            *(float4*)(&xs[n][k4 * 4]) = v;
        }
        __syncthreads();

        float4 acc[8];
#pragma unroll
        for (int j = 0; j < 8; ++j) acc[j] = make_float4(0.f, 0.f, 0.f, 0.f);

        const float4* W4 = (const float4*)W;
#pragma unroll 4
        for (int k = 0; k < K; ++k) {
            float4 w = W4[k * 32 + cq];
#pragma unroll
            for (int j = 0; j < 8; ++j) {
                float xv = xs[nr * 8 + j][k];
                acc[j].x = fmaf(xv, w.x, acc[j].x);
                acc[j].y = fmaf(xv, w.y, acc[j].y);
                acc[j].z = fmaf(xv, w.z, acc[j].z);
                acc[j].w = fmaf(xv, w.w, acc[j].w);
            }
        }

        // ---- epilogue: store h + attention row-dots ----
#pragma unroll
        for (int j = 0; j < 8; ++j) {
            int n = nr * 8 + j;
            bool ok = (n < nrem);
            if (ok) ((float4*)(h + (size_t)(n0 + n) * 128))[cq] = acc[j];
            float ps = acc[j].x * atS.x + acc[j].y * atS.y + acc[j].z * atS.z + acc[j].w * atS.w;
            float pd = acc[j].x * atD.x + acc[j].y * atD.y + acc[j].z * atD.z + acc[j].w * atD.w;
            ps += __shfl_xor(ps, 1); pd += __shfl_xor(pd, 1);
            ps += __shfl_xor(ps, 2); pd += __shfl_xor(pd, 2);
            ps += __shfl_xor(ps, 4); pd += __shfl_xor(pd, 4);
            if (ok && (cq & 7) == 0) {
                int hd = cq >> 3;
                as_[(size_t)(n0 + n) * 4 + hd] = ps;
                ad_[(size_t)(n0 + n) * 4 + hd] = pd;
            }
        }
        __syncthreads();
    }
}

// ================= CSR build =================
__global__ __launch_bounds__(256) void k_hist(const int* __restrict__ ei,
        int* __restrict__ deg, int E)
{
    int i = blockIdx.x * blockDim.x + threadIdx.x;
    int stride = gridDim.x * blockDim.x;
    for (int e = i; e < E; e += stride) atomicAdd(&deg[ei[E + e]], 1);
}

__global__ __launch_bounds__(1024) void k_scan(const int* __restrict__ deg,
        int* __restrict__ rowPtr, int* __restrict__ cursor, int N)
{
    __shared__ int part[1024];
    int t = threadIdx.x;
    int chunk = (N + 1023) >> 10;
    int lo = t * chunk, hi = lo + chunk; if (hi > N) hi = N; if (lo > N) lo = N;
    int s = 0;
    for (int i = lo; i < hi; ++i) s += deg[i];
    part[t] = s;
    __syncthreads();
    for (int off = 1; off < 1024; off <<= 1) {
        int v = (t >= off) ? part[t - off] : 0;
        __syncthreads();
        part[t] += v;
        __syncthreads();
    }
    int run = (t == 0) ? 0 : part[t - 1];
    for (int i = lo; i < hi; ++i) {
        rowPtr[i] = run; cursor[i] = run; run += deg[i];
    }
    if (t == 1023) rowPtr[N] = part[1023];
}

__global__ __launch_bounds__(256) void k_scatter(const int* __restrict__ ei,
        int* __restrict__ cursor, int* __restrict__ sSrc, int E)
{
    int i = blockIdx.x * blockDim.x + threadIdx.x;
    int stride = gridDim.x * blockDim.x;
    for (int e = i; e < E; e += stride) {
        int s = ei[e], d = ei[E + e];
        int pos = atomicAdd(&cursor[d], 1);
        sSrc[pos] = s;
    }
}

// ================= fused softmax + aggregation (CSR, no atomics) =================
// Block = 256 threads = 2 dst-groups of 128. c = channel, hd = head.
__global__ __launch_bounds__(256) void k_agg(const int* __restrict__ rowPtr,
        const int* __restrict__ sSrc,
        const float* __restrict__ as_, const float* __restrict__ ad_,
        const float* __restrict__ h, float* __restrict__ out, int N)
{
    int g = threadIdx.x >> 7;
    int c = threadIdx.x & 127;
    int hd = c >> 5;
    int d = blockIdx.x * 2 + g;
    if (d >= N) return;
    int b0 = rowPtr[d], b1 = rowPtr[d + 1];
    float adv = ad_[(size_t)d * 4 + hd];

    float m = -__builtin_inff();
    for (int j = b0; j < b1; ++j) {
        int s = sSrc[j];
        float v = lrelu(as_[(size_t)s * 4 + hd] + adv);
        m = fmaxf(m, v);
    }
    float sum = 0.f, acc = 0.f;
    for (int j = b0; j < b1; ++j) {
        int s = sSrc[j];
        float v = lrelu(as_[(size_t)s * 4 + hd] + adv);
        float w = __expf(v - m);
        sum += w;
        acc = fmaf(w, h[(size_t)s * 128 + c], acc);
    }
    out[(size_t)d * 128 + c] = acc / (sum + 1e-16f);
}

// ================= BN stats =================
__global__ __launch_bounds__(256) void k_bnstats(const float* __restrict__ x,
        double* __restrict__ sums, int N)
{
    int c = threadIdx.x & 127;
    int n = blockIdx.x * 2 + (threadIdx.x >> 7);
    int rstride = gridDim.x * 2;
    float s1 = 0.f, s2 = 0.f;
    for (; n < N; n += rstride) { float v = x[(size_t)n * 128 + c]; s1 += v; s2 += v * v; }
    atomicAdd(&sums[c], (double)s1);
    atomicAdd(&sums[128 + c], (double)s2);
}

__global__ __launch_bounds__(128) void k_bnscale(const double* __restrict__ sums,
        const float* __restrict__ gamma, const float* __restrict__ beta,
        float* __restrict__ scale, float* __restrict__ shift, int N)
{
    int c = threadIdx.x;
    double mu = sums[c] / (double)N;
    double var = sums[128 + c] / (double)N - mu * mu;
    if (var < 0.0) var = 0.0;
    double rs = 1.0 / sqrt(var + 1e-5);
    float sc = (float)((double)gamma[c] * rs);
    scale[c] = sc;
    shift[c] = beta[c] - (float)mu * sc;
}

// ================= pool =================
__global__ __launch_bounds__(128) void k_pool(const float* __restrict__ x,
        const int* __restrict__ batch, const float* __restrict__ scale, const float* __restrict__ shift,
        float* __restrict__ gsum, float* __restrict__ gcnt, int N)
{
    int c = threadIdx.x;
    int n0 = blockIdx.x * 64;
    if (n0 >= N) return;
    int n1 = n0 + 64; if (n1 > N) n1 = N;
    float sc = scale[c], sh = shift[c];
    float acc = 0.f; int cnt = 0; int cur = batch[n0];
    for (int n = n0; n < n1; ++n) {
        int g = batch[n];
        if (g != cur) {
            atomicAdd(&gsum[cur * 128 + c], acc);
            if (c == 0) atomicAdd(&gcnt[cur], (float)cnt);
            acc = 0.f; cnt = 0; cur = g;
        }
        float v = fmaf(x[(size_t)n * 128 + c], sc, sh);
        acc += (v > 0.f ? v : 0.f);
        cnt++;
    }
    atomicAdd(&gsum[cur * 128 + c], acc);
    if (c == 0) atomicAdd(&gcnt[cur], (float)cnt);
}

// ================= dense head (single block) =================
__global__ __launch_bounds__(256) void k_head(const float* __restrict__ gsum, const float* __restrict__ gcnt,
        const float* __restrict__ d1W, const float* __restrict__ d1b,
        const float* __restrict__ g_d1, const float* __restrict__ b_d1,
        const float* __restrict__ d2W, const float* __restrict__ d2b,
        const float* __restrict__ g_d2, const float* __restrict__ b_d2,
        const float* __restrict__ fcW, const float* __restrict__ fcb,
        float* __restrict__ out)
{
    __shared__ float G[64 * 128];
    __shared__ float Y1[64 * 64];
    __shared__ float Y2[64 * 32];
    int t = threadIdx.x;
    for (int i = t; i < 64 * 128; i += 256) {
        int g = i >> 7;
        float cv = gcnt[g]; if (cv < 1.f) cv = 1.f;
        G[i] = gsum[i] / cv;
    }
    __syncthreads();
    for (int i = t; i < 64 * 64; i += 256) {
        int r = i >> 6, j = i & 63;
        float a = 0.f;
        for (int k = 0; k < 128; ++k) a = fmaf(G[r * 128 + k], d1W[k * 64 + j], a);
        Y1[i] = a + d1b[j];
    }
    __syncthreads();
    if (t < 64) {
        float s1 = 0.f, s2 = 0.f;
        for (int r = 0; r < 64; ++r) { float v = Y1[r * 64 + t]; s1 += v; s2 += v * v; }
        float mu = s1 / 64.f, var = s2 / 64.f - mu * mu; if (var < 0.f) var = 0.f;
        float rs = 1.0f / sqrtf(var + 1e-5f);
        float scv = g_d1[t] * rs, shv = b_d1[t] - mu * scv;
        for (int r = 0; r < 64; ++r) {
            float v = fmaf(Y1[r * 64 + t], scv, shv);
            Y1[r * 64 + t] = v > 0.f ? v : 0.f;
        }
    }
    __syncthreads();
    for (int i = t; i < 64 * 32; i += 256) {
        int r = i >> 5, j = i & 31;
        float a = 0.f;
        for (int k = 0; k < 64; ++k) a = fmaf(Y1[r * 64 + k], d2W[k * 32 + j], a);
        Y2[i] = a + d2b[j];
    }
    __syncthreads();
    if (t < 32) {
        float s1 = 0.f, s2 = 0.f;
        for (int r = 0; r < 64; ++r) { float v = Y2[r * 32 + t]; s1 += v; s2 += v * v; }
        float mu = s1 / 64.f, var = s2 / 64.f - mu * mu; if (var < 0.f) var = 0.f;
        float rs = 1.0f / sqrtf(var + 1e-5f);
        float scv = g_d2[t] * rs, shv = b_d2[t] - mu * scv;
        for (int r = 0; r < 64; ++r) {
            float v = fmaf(Y2[r * 32 + t], scv, shv);
            Y2[r * 32 + t] = v > 0.f ? v : 0.f;
        }
    }
    __syncthreads();
    {
        int r = t >> 2, j = t & 3;
        float a = 0.f;
        for (int k = 0; k < 32; ++k) a = fmaf(Y2[r * 32 + k], fcW[k * 4 + j], a);
        out[t] = a + fcb[j];
    }
}

extern "C" void kernel_launch(void* const* d_in, const int* in_sizes, int n_in,
                              void* d_out, int out_size, void* d_ws, size_t ws_size,
                              hipStream_t stream) {
    const int N = in_sizes[0] / 16;
    const int E = in_sizes[1] / 2;

    const float* x        = (const float*)d_in[0];
    const int*   ei       = (const int*)d_in[1];
    const int*   batch    = (const int*)d_in[2];
    const float* W1       = (const float*)d_in[3];
    const float* att_s1   = (const float*)d_in[5];
    const float* att_d1   = (const float*)d_in[6];
    const float* bn_g1    = (const float*)d_in[7];
    const float* bn_b1    = (const float*)d_in[8];
    const float* W2       = (const float*)d_in[9];
    const float* att_s2   = (const float*)d_in[11];
    const float* att_d2   = (const float*)d_in[12];
    const float* bn_g2    = (const float*)d_in[13];
    const float* bn_b2    = (const float*)d_in[14];
    const float* d1W      = (const float*)d_in[15];
    const float* d1b      = (const float*)d_in[16];
    const float* g_d1     = (const float*)d_in[17];
    const float* b_d1     = (const float*)d_in[18];
    const float* d2W      = (const float*)d_in[19];
    const float* d2b      = (const float*)d_in[20];
    const float* g_d2     = (const float*)d_in[21];
    const float* b_d2     = (const float*)d_in[22];
    const float* fcW      = (const float*)d_in[23];
    const float* fcb      = (const float*)d_in[24];
    float* out = (float*)d_out;

    float* ws = (float*)d_ws;
    size_t o = 0;
    float* hbuf   = ws + o;  o += (size_t)N * 128;
    float* outb   = ws + o;  o += (size_t)N * 128;
    float* as_    = ws + o;  o += (size_t)N * 4;
    float* ad_    = ws + o;  o += (size_t)N * 4;
    float* scale1 = ws + o;  o += 128;
    float* shift1 = ws + o;  o += 128;
    float* scale2 = ws + o;  o += 128;
    float* shift2 = ws + o;  o += 128;
    // ---- zero region (one memset): bnsum, gsum, gcnt, deg ----
    size_t zoff = o;
    double* bnsum = (double*)(ws + o); o += 512;      // 256 doubles (8B-aligned: o even here)
    float* gsum   = ws + o;  o += 64 * 128;
    float* gcnt   = ws + o;  o += 64;
    int*   deg    = (int*)(ws + o); o += N;
    size_t zbytes = (o - zoff) * 4;
    // ---- no-zero-needed ----
    int* rowPtr = (int*)(ws + o); o += (size_t)N + 1;
    int* cursor = (int*)(ws + o); o += N;
    int* sSrc   = (int*)(ws + o); o += E;

    hipMemsetAsync(ws + zoff, 0, zbytes, stream);

    // ---- CSR build (shared by both layers) ----
    k_hist<<<2048, 256, 0, stream>>>(ei, deg, E);
    k_scan<<<1, 1024, 0, stream>>>(deg, rowPtr, cursor, N);
    k_scatter<<<2048, 256, 0, stream>>>(ei, cursor, sSrc, E);

    int gemm_grid = (N + 63) / 64;
    int agg_grid = (N + 1) / 2;

    // ---- layer 1 ----
    k_gemm<16, false><<<gemm_grid, 256, 0, stream>>>(x, W1, nullptr, nullptr,
            att_s1, att_d1, hbuf, as_, ad_, N);
    k_agg<<<agg_grid, 256, 0, stream>>>(rowPtr, sSrc, as_, ad_, hbuf, outb, N);
    k_bnstats<<<2048, 256, 0, stream>>>(outb, bnsum, N);
    k_bnscale<<<1, 128, 0, stream>>>(bnsum, bn_g1, bn_b1, scale1, shift1, N);

    hipMemsetAsync((void*)bnsum, 0, 512 * 4, stream);

    // ---- layer 2 ----
    k_gemm<128, true><<<gemm_grid, 256, 0, stream>>>(outb, W2, scale1, shift1,
            att_s2, att_d2, hbuf, as_, ad_, N);
    k_agg<<<agg_grid, 256, 0, stream>>>(rowPtr, sSrc, as_, ad_, hbuf, outb, N);
    k_bnstats<<<2048, 256, 0, stream>>>(outb, bnsum, N);
    k_bnscale<<<1, 128, 0, stream>>>(bnsum, bn_g2, bn_b2, scale2, shift2, N);

    // ---- pool + head ----
    k_pool<<<(N + 63) / 64, 128, 0, stream>>>(outb, batch, scale2, shift2, gsum, gcnt, N);
    k_head<<<1, 256, 0, stream>>>(gsum, gcnt, d1W, d1b, g_d1, b_d1,
                                  d2W, d2b, g_d2, b_d2, fcW, fcb, out);
}

// Round 3
// 1046.474 us; speedup vs baseline: 4.2507x; 1.6386x over previous
//
#include <hip/hip_runtime.h>

#define HID 128
#define NG 64

__device__ __forceinline__ float lrelu(float v) { return v > 0.0f ? v : 0.2f * v; }

// ================= unified node-transform GEMM =================
// h[n][c] = sum_k act(xin[n][k]) * W[k][c];  also a_s[n][hd], a_d[n][hd]
// Block: 256 threads. Tile: 64 nodes x 128 channels.
// Thread (cq = t&31, nr = t>>5): nodes nr*8..+7, channels cq*4..+3.
template <int K, bool BN>
__global__ __launch_bounds__(256) void k_gemm(const float* __restrict__ xin,
        const float* __restrict__ W,
        const float* __restrict__ scale, const float* __restrict__ shift,
        const float* __restrict__ attS, const float* __restrict__ attD,
        float* __restrict__ h, float* __restrict__ as_, float* __restrict__ ad_, int N)
{
    __shared__ float xs[64][K];
    constexpr int K4 = K / 4;
    int t = threadIdx.x;
    int cq = t & 31;
    int nr = t >> 5;

    float4 atS = ((const float4*)attS)[cq];
    float4 atD = ((const float4*)attD)[cq];

    for (int n0 = blockIdx.x * 64; n0 < N; n0 += gridDim.x * 64) {
        int nrem = N - n0; if (nrem > 64) nrem = 64;
        for (int idx = t; idx < 64 * K4; idx += 256) {
            int n = idx / K4, k4 = idx % K4;
            float4 v = make_float4(0.f, 0.f, 0.f, 0.f);
            if (n < nrem) {
                v = ((const float4*)(xin + (size_t)(n0 + n) * K))[k4];
                if (BN) {
                    float4 sc = ((const float4*)scale)[k4];
                    float4 sh = ((const float4*)shift)[k4];
                    v.x = fmaf(v.x, sc.x, sh.x); v.x = v.x > 0.f ? v.x : 0.f;
                    v.y = fmaf(v.y, sc.y, sh.y); v.y = v.y > 0.f ? v.y : 0.f;
                    v.z = fmaf(v.z, sc.z, sh.z); v.z = v.z > 0.f ? v.z : 0.f;
                    v.w = fmaf(v.w, sc.w, sh.w); v.w = v.w > 0.f ? v.w : 0.f;
                }
            }
            *(float4*)(&xs[n][k4 * 4]) = v;
        }
        __syncthreads();

        float4 acc[8];
#pragma unroll
        for (int j = 0; j < 8; ++j) acc[j] = make_float4(0.f, 0.f, 0.f, 0.f);

        const float4* W4 = (const float4*)W;
#pragma unroll 2
        for (int k4 = 0; k4 < K4; ++k4) {
            float4 w0 = W4[(k4 * 4 + 0) * 32 + cq];
            float4 w1 = W4[(k4 * 4 + 1) * 32 + cq];
            float4 w2 = W4[(k4 * 4 + 2) * 32 + cq];
            float4 w3 = W4[(k4 * 4 + 3) * 32 + cq];
#pragma unroll
            for (int j = 0; j < 8; ++j) {
                float4 xv = *(const float4*)(&xs[nr * 8 + j][k4 * 4]);
                acc[j].x = fmaf(xv.x, w0.x, acc[j].x);
                acc[j].y = fmaf(xv.x, w0.y, acc[j].y);
                acc[j].z = fmaf(xv.x, w0.z, acc[j].z);
                acc[j].w = fmaf(xv.x, w0.w, acc[j].w);
                acc[j].x = fmaf(xv.y, w1.x, acc[j].x);
                acc[j].y = fmaf(xv.y, w1.y, acc[j].y);
                acc[j].z = fmaf(xv.y, w1.z, acc[j].z);
                acc[j].w = fmaf(xv.y, w1.w, acc[j].w);
                acc[j].x = fmaf(xv.z, w2.x, acc[j].x);
                acc[j].y = fmaf(xv.z, w2.y, acc[j].y);
                acc[j].z = fmaf(xv.z, w2.z, acc[j].z);
                acc[j].w = fmaf(xv.z, w2.w, acc[j].w);
                acc[j].x = fmaf(xv.w, w3.x, acc[j].x);
                acc[j].y = fmaf(xv.w, w3.y, acc[j].y);
                acc[j].z = fmaf(xv.w, w3.z, acc[j].z);
                acc[j].w = fmaf(xv.w, w3.w, acc[j].w);
            }
        }

#pragma unroll
        for (int j = 0; j < 8; ++j) {
            int n = nr * 8 + j;
            bool ok = (n < nrem);
            if (ok) ((float4*)(h + (size_t)(n0 + n) * 128))[cq] = acc[j];
            float ps = acc[j].x * atS.x + acc[j].y * atS.y + acc[j].z * atS.z + acc[j].w * atS.w;
            float pd = acc[j].x * atD.x + acc[j].y * atD.y + acc[j].z * atD.z + acc[j].w * atD.w;
            ps += __shfl_xor(ps, 1); pd += __shfl_xor(pd, 1);
            ps += __shfl_xor(ps, 2); pd += __shfl_xor(pd, 2);
            ps += __shfl_xor(ps, 4); pd += __shfl_xor(pd, 4);
            if (ok && (cq & 7) == 0) {
                int hd = cq >> 3;
                as_[(size_t)(n0 + n) * 4 + hd] = ps;
                ad_[(size_t)(n0 + n) * 4 + hd] = pd;
            }
        }
        __syncthreads();
    }
}

// ================= CSR build =================
__global__ __launch_bounds__(256) void k_hist(const int* __restrict__ ei,
        int* __restrict__ deg, int E)
{
    int i = blockIdx.x * blockDim.x + threadIdx.x;
    int stride = gridDim.x * blockDim.x;
    for (int e = i; e < E; e += stride) atomicAdd(&deg[ei[E + e]], 1);
}

__global__ __launch_bounds__(1024) void k_scan(const int* __restrict__ deg,
        int* __restrict__ rowPtr, int* __restrict__ cursor, int N)
{
    __shared__ int part[1024];
    int t = threadIdx.x;
    int chunk = (N + 1023) >> 10;
    int lo = t * chunk, hi = lo + chunk; if (hi > N) hi = N; if (lo > N) lo = N;
    int s = 0;
    for (int i = lo; i < hi; ++i) s += deg[i];
    part[t] = s;
    __syncthreads();
    for (int off = 1; off < 1024; off <<= 1) {
        int v = (t >= off) ? part[t - off] : 0;
        __syncthreads();
        part[t] += v;
        __syncthreads();
    }
    int run = (t == 0) ? 0 : part[t - 1];
    for (int i = lo; i < hi; ++i) {
        rowPtr[i] = run; cursor[i] = run; run += deg[i];
    }
    if (t == 1023) rowPtr[N] = part[1023];
}

__global__ __launch_bounds__(256) void k_scatter(const int* __restrict__ ei,
        int* __restrict__ cursor, int* __restrict__ sSrc, int E)
{
    int i = blockIdx.x * blockDim.x + threadIdx.x;
    int stride = gridDim.x * blockDim.x;
    for (int e = i; e < E; e += stride) {
        int s = ei[e], d = ei[E + e];
        int pos = atomicAdd(&cursor[d], 1);
        sSrc[pos] = s;
    }
}

// ================= attention weights: w = exp(v - max), per-dst head sums =================
// 8 lanes per dst; block 256 -> 32 dsts.
__global__ __launch_bounds__(256) void k_alpha(const int* __restrict__ rowPtr,
        const int* __restrict__ sSrc,
        const float* __restrict__ as_, const float* __restrict__ ad_,
        float* __restrict__ alpha, float* __restrict__ sums, int N)
{
    int t = threadIdx.x;
    int lane8 = t & 7;
    int d = blockIdx.x * 32 + (t >> 3);
    if (d >= N) return;
    int b0 = rowPtr[d], b1 = rowPtr[d + 1];
    float4 adv = ((const float4*)ad_)[d];

    float4 m = make_float4(-3.4e38f, -3.4e38f, -3.4e38f, -3.4e38f);
    for (int j = b0 + lane8; j < b1; j += 8) {
        int s = sSrc[j];
        float4 a = ((const float4*)as_)[s];
        m.x = fmaxf(m.x, lrelu(a.x + adv.x));
        m.y = fmaxf(m.y, lrelu(a.y + adv.y));
        m.z = fmaxf(m.z, lrelu(a.z + adv.z));
        m.w = fmaxf(m.w, lrelu(a.w + adv.w));
    }
#pragma unroll
    for (int off = 1; off < 8; off <<= 1) {
        m.x = fmaxf(m.x, __shfl_xor(m.x, off));
        m.y = fmaxf(m.y, __shfl_xor(m.y, off));
        m.z = fmaxf(m.z, __shfl_xor(m.z, off));
        m.w = fmaxf(m.w, __shfl_xor(m.w, off));
    }
    float4 sum = make_float4(0.f, 0.f, 0.f, 0.f);
    for (int j = b0 + lane8; j < b1; j += 8) {
        int s = sSrc[j];
        float4 a = ((const float4*)as_)[s];
        float4 w;
        w.x = __expf(lrelu(a.x + adv.x) - m.x);
        w.y = __expf(lrelu(a.y + adv.y) - m.y);
        w.z = __expf(lrelu(a.z + adv.z) - m.z);
        w.w = __expf(lrelu(a.w + adv.w) - m.w);
        ((float4*)alpha)[j] = w;
        sum.x += w.x; sum.y += w.y; sum.z += w.z; sum.w += w.w;
    }
#pragma unroll
    for (int off = 1; off < 8; off <<= 1) {
        sum.x += __shfl_xor(sum.x, off);
        sum.y += __shfl_xor(sum.y, off);
        sum.z += __shfl_xor(sum.z, off);
        sum.w += __shfl_xor(sum.w, off);
    }
    if (lane8 == 0) ((float4*)sums)[d] = sum;
}

// ================= CSR SpMM aggregation =================
// 32 threads per dst (float4 channels); block 256 -> 8 dsts. Unroll x4 for MLP.
__global__ __launch_bounds__(256) void k_agg(const int* __restrict__ rowPtr,
        const int* __restrict__ sSrc,
        const float* __restrict__ alpha, const float* __restrict__ sums,
        const float* __restrict__ h, float* __restrict__ out, int N)
{
    int t = threadIdx.x;
    int lane = t & 31;
    int d = blockIdx.x * 8 + (t >> 5);
    if (d >= N) return;
    int hd = lane >> 3;
    int b0 = rowPtr[d], b1 = rowPtr[d + 1];
    const float4* h4 = (const float4*)h;

    float4 acc = make_float4(0.f, 0.f, 0.f, 0.f);
    int j = b0;
    for (; j + 4 <= b1; j += 4) {
        int s0 = sSrc[j], s1 = sSrc[j + 1], s2 = sSrc[j + 2], s3 = sSrc[j + 3];
        float w0 = alpha[(size_t)j * 4 + hd];
        float w1 = alpha[(size_t)(j + 1) * 4 + hd];
        float w2 = alpha[(size_t)(j + 2) * 4 + hd];
        float w3 = alpha[(size_t)(j + 3) * 4 + hd];
        float4 h0 = h4[(size_t)s0 * 32 + lane];
        float4 h1 = h4[(size_t)s1 * 32 + lane];
        float4 h2 = h4[(size_t)s2 * 32 + lane];
        float4 h3 = h4[(size_t)s3 * 32 + lane];
        acc.x = fmaf(w0, h0.x, acc.x); acc.y = fmaf(w0, h0.y, acc.y);
        acc.z = fmaf(w0, h0.z, acc.z); acc.w = fmaf(w0, h0.w, acc.w);
        acc.x = fmaf(w1, h1.x, acc.x); acc.y = fmaf(w1, h1.y, acc.y);
        acc.z = fmaf(w1, h1.z, acc.z); acc.w = fmaf(w1, h1.w, acc.w);
        acc.x = fmaf(w2, h2.x, acc.x); acc.y = fmaf(w2, h2.y, acc.y);
        acc.z = fmaf(w2, h2.z, acc.z); acc.w = fmaf(w2, h2.w, acc.w);
        acc.x = fmaf(w3, h3.x, acc.x); acc.y = fmaf(w3, h3.y, acc.y);
        acc.z = fmaf(w3, h3.z, acc.z); acc.w = fmaf(w3, h3.w, acc.w);
    }
    for (; j < b1; ++j) {
        int s = sSrc[j];
        float w = alpha[(size_t)j * 4 + hd];
        float4 hv = h4[(size_t)s * 32 + lane];
        acc.x = fmaf(w, hv.x, acc.x); acc.y = fmaf(w, hv.y, acc.y);
        acc.z = fmaf(w, hv.z, acc.z); acc.w = fmaf(w, hv.w, acc.w);
    }
    float inv = 1.f / (sums[(size_t)d * 4 + hd] + 1e-16f);
    acc.x *= inv; acc.y *= inv; acc.z *= inv; acc.w *= inv;
    ((float4*)out)[(size_t)d * 32 + lane] = acc;
}

// ================= BN stats =================
__global__ __launch_bounds__(256) void k_bnstats(const float* __restrict__ x,
        double* __restrict__ sums, int N)
{
    __shared__ float r1[256], r2[256];
    int t = threadIdx.x;
    int c = t & 127;
    int half = t >> 7;
    float s1 = 0.f, s2 = 0.f;
    for (int n = blockIdx.x * 2 + half; n < N; n += gridDim.x * 2) {
        float v = x[(size_t)n * 128 + c];
        s1 += v; s2 += v * v;
    }
    r1[t] = s1; r2[t] = s2;
    __syncthreads();
    if (t < 128) {
        s1 = r1[t] + r1[t + 128];
        s2 = r2[t] + r2[t + 128];
        atomicAdd(&sums[t], (double)s1);
        atomicAdd(&sums[128 + t], (double)s2);
    }
}

__global__ __launch_bounds__(128) void k_bnscale(const double* __restrict__ sums,
        const float* __restrict__ gamma, const float* __restrict__ beta,
        float* __restrict__ scale, float* __restrict__ shift, int N)
{
    int c = threadIdx.x;
    double mu = sums[c] / (double)N;
    double var = sums[128 + c] / (double)N - mu * mu;
    if (var < 0.0) var = 0.0;
    double rs = 1.0 / sqrt(var + 1e-5);
    float sc = (float)((double)gamma[c] * rs);
    scale[c] = sc;
    shift[c] = beta[c] - (float)mu * sc;
}

// ================= pool (float4 lanes, run-length per subgroup) =================
__global__ __launch_bounds__(128) void k_pool(const float* __restrict__ x,
        const int* __restrict__ batch, const float* __restrict__ scale, const float* __restrict__ shift,
        float* __restrict__ gsum, float* __restrict__ gcnt, int N)
{
    int lane = threadIdx.x & 31;
    int r = threadIdx.x >> 5;
    int n0 = blockIdx.x * 64;
    if (n0 >= N) return;
    int n1 = n0 + 64; if (n1 > N) n1 = N;
    float4 sc = ((const float4*)scale)[lane];
    float4 sh = ((const float4*)shift)[lane];
    float4 acc = make_float4(0.f, 0.f, 0.f, 0.f);
    int cnt = 0, cur = -1;
    for (int n = n0 + r; n < n1; n += 4) {
        int g = batch[n];
        if (g != cur) {
            if (cur >= 0) {
                atomicAdd(&gsum[cur * 128 + lane * 4 + 0], acc.x);
                atomicAdd(&gsum[cur * 128 + lane * 4 + 1], acc.y);
                atomicAdd(&gsum[cur * 128 + lane * 4 + 2], acc.z);
                atomicAdd(&gsum[cur * 128 + lane * 4 + 3], acc.w);
                if (lane == 0) atomicAdd(&gcnt[cur], (float)cnt);
            }
            acc = make_float4(0.f, 0.f, 0.f, 0.f); cnt = 0; cur = g;
        }
        float4 v = ((const float4*)x)[(size_t)n * 32 + lane];
        v.x = fmaf(v.x, sc.x, sh.x); v.x = v.x > 0.f ? v.x : 0.f;
        v.y = fmaf(v.y, sc.y, sh.y); v.y = v.y > 0.f ? v.y : 0.f;
        v.z = fmaf(v.z, sc.z, sh.z); v.z = v.z > 0.f ? v.z : 0.f;
        v.w = fmaf(v.w, sc.w, sh.w); v.w = v.w > 0.f ? v.w : 0.f;
        acc.x += v.x; acc.y += v.y; acc.z += v.z; acc.w += v.w;
        cnt++;
    }
    if (cur >= 0) {
        atomicAdd(&gsum[cur * 128 + lane * 4 + 0], acc.x);
        atomicAdd(&gsum[cur * 128 + lane * 4 + 1], acc.y);
        atomicAdd(&gsum[cur * 128 + lane * 4 + 2], acc.z);
        atomicAdd(&gsum[cur * 128 + lane * 4 + 3], acc.w);
        if (lane == 0) atomicAdd(&gcnt[cur], (float)cnt);
    }
}

// ================= dense head (single block) =================
__global__ __launch_bounds__(256) void k_head(const float* __restrict__ gsum, const float* __restrict__ gcnt,
        const float* __restrict__ d1W, const float* __restrict__ d1b,
        const float* __restrict__ g_d1, const float* __restrict__ b_d1,
        const float* __restrict__ d2W, const float* __restrict__ d2b,
        const float* __restrict__ g_d2, const float* __restrict__ b_d2,
        const float* __restrict__ fcW, const float* __restrict__ fcb,
        float* __restrict__ out)
{
    __shared__ float G[64 * 128];
    __shared__ float Y1[64 * 64];
    __shared__ float Y2[64 * 32];
    int t = threadIdx.x;
    for (int i = t; i < 64 * 128; i += 256) {
        int g = i >> 7;
        float cv = gcnt[g]; if (cv < 1.f) cv = 1.f;
        G[i] = gsum[i] / cv;
    }
    __syncthreads();
    for (int i = t; i < 64 * 64; i += 256) {
        int r = i >> 6, j = i & 63;
        float a = 0.f;
        for (int k = 0; k < 128; ++k) a = fmaf(G[r * 128 + k], d1W[k * 64 + j], a);
        Y1[i] = a + d1b[j];
    }
    __syncthreads();
    if (t < 64) {
        float s1 = 0.f, s2 = 0.f;
        for (int r = 0; r < 64; ++r) { float v = Y1[r * 64 + t]; s1 += v; s2 += v * v; }
        float mu = s1 / 64.f, var = s2 / 64.f - mu * mu; if (var < 0.f) var = 0.f;
        float rs = 1.0f / sqrtf(var + 1e-5f);
        float scv = g_d1[t] * rs, shv = b_d1[t] - mu * scv;
        for (int r = 0; r < 64; ++r) {
            float v = fmaf(Y1[r * 64 + t], scv, shv);
            Y1[r * 64 + t] = v > 0.f ? v : 0.f;
        }
    }
    __syncthreads();
    for (int i = t; i < 64 * 32; i += 256) {
        int r = i >> 5, j = i & 31;
        float a = 0.f;
        for (int k = 0; k < 64; ++k) a = fmaf(Y1[r * 64 + k], d2W[k * 32 + j], a);
        Y2[i] = a + d2b[j];
    }
    __syncthreads();
    if (t < 32) {
        float s1 = 0.f, s2 = 0.f;
        for (int r = 0; r < 64; ++r) { float v = Y2[r * 32 + t]; s1 += v; s2 += v * v; }
        float mu = s1 / 64.f, var = s2 / 64.f - mu * mu; if (var < 0.f) var = 0.f;
        float rs = 1.0f / sqrtf(var + 1e-5f);
        float scv = g_d2[t] * rs, shv = b_d2[t] - mu * scv;
        for (int r = 0; r < 64; ++r) {
            float v = fmaf(Y2[r * 32 + t], scv, shv);
            Y2[r * 32 + t] = v > 0.f ? v : 0.f;
        }
    }
    __syncthreads();
    {
        int r = t >> 2, j = t & 3;
        float a = 0.f;
        for (int k = 0; k < 32; ++k) a = fmaf(Y2[r * 32 + k], fcW[k * 4 + j], a);
        out[t] = a + fcb[j];
    }
}

extern "C" void kernel_launch(void* const* d_in, const int* in_sizes, int n_in,
                              void* d_out, int out_size, void* d_ws, size_t ws_size,
                              hipStream_t stream) {
    const int N = in_sizes[0] / 16;
    const int E = in_sizes[1] / 2;

    const float* x        = (const float*)d_in[0];
    const int*   ei       = (const int*)d_in[1];
    const int*   batch    = (const int*)d_in[2];
    const float* W1       = (const float*)d_in[3];
    const float* att_s1   = (const float*)d_in[5];
    const float* att_d1   = (const float*)d_in[6];
    const float* bn_g1    = (const float*)d_in[7];
    const float* bn_b1    = (const float*)d_in[8];
    const float* W2       = (const float*)d_in[9];
    const float* att_s2   = (const float*)d_in[11];
    const float* att_d2   = (const float*)d_in[12];
    const float* bn_g2    = (const float*)d_in[13];
    const float* bn_b2    = (const float*)d_in[14];
    const float* d1W      = (const float*)d_in[15];
    const float* d1b      = (const float*)d_in[16];
    const float* g_d1     = (const float*)d_in[17];
    const float* b_d1     = (const float*)d_in[18];
    const float* d2W      = (const float*)d_in[19];
    const float* d2b      = (const float*)d_in[20];
    const float* g_d2     = (const float*)d_in[21];
    const float* b_d2     = (const float*)d_in[22];
    const float* fcW      = (const float*)d_in[23];
    const float* fcb      = (const float*)d_in[24];
    float* out = (float*)d_out;

    float* ws = (float*)d_ws;
    size_t o = 0;
    float* hbuf   = ws + o;  o += (size_t)N * 128;
    float* outb   = ws + o;  o += (size_t)N * 128;
    float* as_    = ws + o;  o += (size_t)N * 4;
    float* ad_    = ws + o;  o += (size_t)N * 4;
    float* alpha  = ws + o;  o += (size_t)E * 4;
    float* sums   = ws + o;  o += (size_t)N * 4;
    float* scale1 = ws + o;  o += 128;
    float* shift1 = ws + o;  o += 128;
    float* scale2 = ws + o;  o += 128;
    float* shift2 = ws + o;  o += 128;
    // ---- zero region (one memset): bnsum, gsum, gcnt, deg ----
    size_t zoff = o;
    double* bnsum = (double*)(ws + o); o += 512;
    float* gsum   = ws + o;  o += 64 * 128;
    float* gcnt   = ws + o;  o += 64;
    int*   deg    = (int*)(ws + o); o += N;
    size_t zbytes = (o - zoff) * 4;
    int* rowPtr = (int*)(ws + o); o += (size_t)N + 1;
    int* cursor = (int*)(ws + o); o += N;
    int* sSrc   = (int*)(ws + o); o += E;

    hipMemsetAsync(ws + zoff, 0, zbytes, stream);

    // ---- CSR build (shared by both layers) ----
    k_hist<<<2048, 256, 0, stream>>>(ei, deg, E);
    k_scan<<<1, 1024, 0, stream>>>(deg, rowPtr, cursor, N);
    k_scatter<<<2048, 256, 0, stream>>>(ei, cursor, sSrc, E);

    int gemm_grid = (N + 63) / 64;
    int alpha_grid = (N + 31) / 32;
    int agg_grid = (N + 7) / 8;

    // ---- layer 1 ----
    k_gemm<16, false><<<gemm_grid, 256, 0, stream>>>(x, W1, nullptr, nullptr,
            att_s1, att_d1, hbuf, as_, ad_, N);
    k_alpha<<<alpha_grid, 256, 0, stream>>>(rowPtr, sSrc, as_, ad_, alpha, sums, N);
    k_agg<<<agg_grid, 256, 0, stream>>>(rowPtr, sSrc, alpha, sums, hbuf, outb, N);
    k_bnstats<<<1024, 256, 0, stream>>>(outb, bnsum, N);
    k_bnscale<<<1, 128, 0, stream>>>(bnsum, bn_g1, bn_b1, scale1, shift1, N);

    hipMemsetAsync((void*)bnsum, 0, 512 * 4, stream);

    // ---- layer 2 ----
    k_gemm<128, true><<<gemm_grid, 256, 0, stream>>>(outb, W2, scale1, shift1,
            att_s2, att_d2, hbuf, as_, ad_, N);
    k_alpha<<<alpha_grid, 256, 0, stream>>>(rowPtr, sSrc, as_, ad_, alpha, sums, N);
    k_agg<<<agg_grid, 256, 0, stream>>>(rowPtr, sSrc, alpha, sums, hbuf, outb, N);
    k_bnstats<<<1024, 256, 0, stream>>>(outb, bnsum, N);
    k_bnscale<<<1, 128, 0, stream>>>(bnsum, bn_g2, bn_b2, scale2, shift2, N);

    // ---- pool + head ----
    k_pool<<<(N + 63) / 64, 128, 0, stream>>>(outb, batch, scale2, shift2, gsum, gcnt, N);
    k_head<<<1, 256, 0, stream>>>(gsum, gcnt, d1W, d1b, g_d1, b_d1,
                                  d2W, d2b, g_d2, b_d2, fcW, fcb, out);
}

// Round 4
// 845.898 us; speedup vs baseline: 5.2586x; 1.2371x over previous
//
#include <hip/hip_runtime.h>

#define HID 128
#define NG 64
#define SCANB 256

__device__ __forceinline__ float lrelu(float v) { return v > 0.0f ? v : 0.2f * v; }

// ================= unified node-transform GEMM =================
template <int K, bool BN>
__global__ __launch_bounds__(256) void k_gemm(const float* __restrict__ xin,
        const float* __restrict__ W,
        const float* __restrict__ scale, const float* __restrict__ shift,
        const float* __restrict__ attS, const float* __restrict__ attD,
        float* __restrict__ h, float* __restrict__ as_, float* __restrict__ ad_, int N)
{
    __shared__ float xs[64][K];
    constexpr int K4 = K / 4;
    int t = threadIdx.x;
    int cq = t & 31;
    int nr = t >> 5;

    float4 atS = ((const float4*)attS)[cq];
    float4 atD = ((const float4*)attD)[cq];

    for (int n0 = blockIdx.x * 64; n0 < N; n0 += gridDim.x * 64) {
        int nrem = N - n0; if (nrem > 64) nrem = 64;
        for (int idx = t; idx < 64 * K4; idx += 256) {
            int n = idx / K4, k4 = idx % K4;
            float4 v = make_float4(0.f, 0.f, 0.f, 0.f);
            if (n < nrem) {
                v = ((const float4*)(xin + (size_t)(n0 + n) * K))[k4];
                if (BN) {
                    float4 sc = ((const float4*)scale)[k4];
                    float4 sh = ((const float4*)shift)[k4];
                    v.x = fmaf(v.x, sc.x, sh.x); v.x = v.x > 0.f ? v.x : 0.f;
                    v.y = fmaf(v.y, sc.y, sh.y); v.y = v.y > 0.f ? v.y : 0.f;
                    v.z = fmaf(v.z, sc.z, sh.z); v.z = v.z > 0.f ? v.z : 0.f;
                    v.w = fmaf(v.w, sc.w, sh.w); v.w = v.w > 0.f ? v.w : 0.f;
                }
            }
            *(float4*)(&xs[n][k4 * 4]) = v;
        }
        __syncthreads();

        float4 acc[8];
#pragma unroll
        for (int j = 0; j < 8; ++j) acc[j] = make_float4(0.f, 0.f, 0.f, 0.f);

        const float4* W4 = (const float4*)W;
#pragma unroll 2
        for (int k4 = 0; k4 < K4; ++k4) {
            float4 w0 = W4[(k4 * 4 + 0) * 32 + cq];
            float4 w1 = W4[(k4 * 4 + 1) * 32 + cq];
            float4 w2 = W4[(k4 * 4 + 2) * 32 + cq];
            float4 w3 = W4[(k4 * 4 + 3) * 32 + cq];
#pragma unroll
            for (int j = 0; j < 8; ++j) {
                float4 xv = *(const float4*)(&xs[nr * 8 + j][k4 * 4]);
                acc[j].x = fmaf(xv.x, w0.x, acc[j].x);
                acc[j].y = fmaf(xv.x, w0.y, acc[j].y);
                acc[j].z = fmaf(xv.x, w0.z, acc[j].z);
                acc[j].w = fmaf(xv.x, w0.w, acc[j].w);
                acc[j].x = fmaf(xv.y, w1.x, acc[j].x);
                acc[j].y = fmaf(xv.y, w1.y, acc[j].y);
                acc[j].z = fmaf(xv.y, w1.z, acc[j].z);
                acc[j].w = fmaf(xv.y, w1.w, acc[j].w);
                acc[j].x = fmaf(xv.z, w2.x, acc[j].x);
                acc[j].y = fmaf(xv.z, w2.y, acc[j].y);
                acc[j].z = fmaf(xv.z, w2.z, acc[j].z);
                acc[j].w = fmaf(xv.z, w2.w, acc[j].w);
                acc[j].x = fmaf(xv.w, w3.x, acc[j].x);
                acc[j].y = fmaf(xv.w, w3.y, acc[j].y);
                acc[j].z = fmaf(xv.w, w3.z, acc[j].z);
                acc[j].w = fmaf(xv.w, w3.w, acc[j].w);
            }
        }

#pragma unroll
        for (int j = 0; j < 8; ++j) {
            int n = nr * 8 + j;
            bool ok = (n < nrem);
            if (ok) ((float4*)(h + (size_t)(n0 + n) * 128))[cq] = acc[j];
            float ps = acc[j].x * atS.x + acc[j].y * atS.y + acc[j].z * atS.z + acc[j].w * atS.w;
            float pd = acc[j].x * atD.x + acc[j].y * atD.y + acc[j].z * atD.z + acc[j].w * atD.w;
            ps += __shfl_xor(ps, 1); pd += __shfl_xor(pd, 1);
            ps += __shfl_xor(ps, 2); pd += __shfl_xor(pd, 2);
            ps += __shfl_xor(ps, 4); pd += __shfl_xor(pd, 4);
            if (ok && (cq & 7) == 0) {
                int hd = cq >> 3;
                as_[(size_t)(n0 + n) * 4 + hd] = ps;
                ad_[(size_t)(n0 + n) * 4 + hd] = pd;
            }
        }
        __syncthreads();
    }
}

// ================= CSR build =================
__global__ __launch_bounds__(256) void k_hist(const int* __restrict__ ei,
        int* __restrict__ deg, int E)
{
    int i = blockIdx.x * blockDim.x + threadIdx.x;
    int stride = gridDim.x * blockDim.x;
    for (int e = i; e < E; e += stride) atomicAdd(&deg[ei[E + e]], 1);
}

// 3-stage grid-parallel exclusive scan of deg -> rowPtr, cursor
__global__ __launch_bounds__(256) void k_scan1(const int* __restrict__ deg,
        int* __restrict__ blockSum, int N)
{
    __shared__ int red[256];
    int b = blockIdx.x;
    int chunkB = (N + SCANB - 1) / SCANB;
    int lo = b * chunkB, hi = lo + chunkB; if (hi > N) hi = N; if (lo > N) lo = N;
    int s = 0;
    for (int i = lo + threadIdx.x; i < hi; i += 256) s += deg[i];
    red[threadIdx.x] = s;
    __syncthreads();
    for (int off = 128; off; off >>= 1) {
        if (threadIdx.x < off) red[threadIdx.x] += red[threadIdx.x + off];
        __syncthreads();
    }
    if (threadIdx.x == 0) blockSum[b] = red[0];
}

__global__ __launch_bounds__(256) void k_scan2(const int* __restrict__ blockSum,
        int* __restrict__ blockOff, int* __restrict__ totalOut)
{
    __shared__ int part[256];
    int t = threadIdx.x;
    part[t] = blockSum[t];
    __syncthreads();
    for (int off = 1; off < 256; off <<= 1) {
        int v = (t >= off) ? part[t - off] : 0;
        __syncthreads();
        part[t] += v;
        __syncthreads();
    }
    blockOff[t] = (t == 0) ? 0 : part[t - 1];
    if (t == 255) *totalOut = part[255];
}

__global__ __launch_bounds__(256) void k_scan3(const int* __restrict__ deg,
        const int* __restrict__ blockOff,
        int* __restrict__ rowPtr, int* __restrict__ cursor, int N)
{
    __shared__ int part[256];
    int b = blockIdx.x;
    int chunkB = (N + SCANB - 1) / SCANB;
    int lo = b * chunkB, hi = lo + chunkB; if (hi > N) hi = N; if (lo > N) lo = N;
    int sub = (chunkB + 255) / 256;
    int tl = lo + threadIdx.x * sub;
    int th = tl + sub; if (th > hi) th = hi; if (tl > hi) tl = hi;
    int s = 0;
    for (int i = tl; i < th; ++i) s += deg[i];
    part[threadIdx.x] = s;
    __syncthreads();
    for (int off = 1; off < 256; off <<= 1) {
        int v = (threadIdx.x >= off) ? part[threadIdx.x - off] : 0;
        __syncthreads();
        part[threadIdx.x] += v;
        __syncthreads();
    }
    int run = blockOff[b] + ((threadIdx.x == 0) ? 0 : part[threadIdx.x - 1]);
    for (int i = tl; i < th; ++i) {
        rowPtr[i] = run; cursor[i] = run; run += deg[i];
    }
}

__global__ __launch_bounds__(256) void k_scatter(const int* __restrict__ ei,
        int* __restrict__ cursor, int* __restrict__ sSrc, int E)
{
    int i = blockIdx.x * blockDim.x + threadIdx.x;
    int stride = gridDim.x * blockDim.x;
    for (int e = i; e < E; e += stride) {
        int s = ei[e], d = ei[E + e];
        int pos = atomicAdd(&cursor[d], 1);
        sSrc[pos] = s;
    }
}

// ================= attention weights =================
__global__ __launch_bounds__(256) void k_alpha(const int* __restrict__ rowPtr,
        const int* __restrict__ sSrc,
        const float* __restrict__ as_, const float* __restrict__ ad_,
        float* __restrict__ alpha, float* __restrict__ sums, int N)
{
    int t = threadIdx.x;
    int lane8 = t & 7;
    int d = blockIdx.x * 32 + (t >> 3);
    if (d >= N) return;
    int b0 = rowPtr[d], b1 = rowPtr[d + 1];
    float4 adv = ((const float4*)ad_)[d];

    float4 m = make_float4(-3.4e38f, -3.4e38f, -3.4e38f, -3.4e38f);
    for (int j = b0 + lane8; j < b1; j += 8) {
        int s = sSrc[j];
        float4 a = ((const float4*)as_)[s];
        m.x = fmaxf(m.x, lrelu(a.x + adv.x));
        m.y = fmaxf(m.y, lrelu(a.y + adv.y));
        m.z = fmaxf(m.z, lrelu(a.z + adv.z));
        m.w = fmaxf(m.w, lrelu(a.w + adv.w));
    }
#pragma unroll
    for (int off = 1; off < 8; off <<= 1) {
        m.x = fmaxf(m.x, __shfl_xor(m.x, off));
        m.y = fmaxf(m.y, __shfl_xor(m.y, off));
        m.z = fmaxf(m.z, __shfl_xor(m.z, off));
        m.w = fmaxf(m.w, __shfl_xor(m.w, off));
    }
    float4 sum = make_float4(0.f, 0.f, 0.f, 0.f);
    for (int j = b0 + lane8; j < b1; j += 8) {
        int s = sSrc[j];
        float4 a = ((const float4*)as_)[s];
        float4 w;
        w.x = __expf(lrelu(a.x + adv.x) - m.x);
        w.y = __expf(lrelu(a.y + adv.y) - m.y);
        w.z = __expf(lrelu(a.z + adv.z) - m.z);
        w.w = __expf(lrelu(a.w + adv.w) - m.w);
        ((float4*)alpha)[j] = w;
        sum.x += w.x; sum.y += w.y; sum.z += w.z; sum.w += w.w;
    }
#pragma unroll
    for (int off = 1; off < 8; off <<= 1) {
        sum.x += __shfl_xor(sum.x, off);
        sum.y += __shfl_xor(sum.y, off);
        sum.z += __shfl_xor(sum.z, off);
        sum.w += __shfl_xor(sum.w, off);
    }
    if (lane8 == 0) ((float4*)sums)[d] = sum;
}

// ================= CSR SpMM aggregation =================
__global__ __launch_bounds__(256) void k_agg(const int* __restrict__ rowPtr,
        const int* __restrict__ sSrc,
        const float* __restrict__ alpha, const float* __restrict__ sums,
        const float* __restrict__ h, float* __restrict__ out, int N)
{
    int t = threadIdx.x;
    int lane = t & 31;
    int d = blockIdx.x * 8 + (t >> 5);
    if (d >= N) return;
    int hd = lane >> 3;
    int b0 = rowPtr[d], b1 = rowPtr[d + 1];
    const float4* h4 = (const float4*)h;

    float4 acc = make_float4(0.f, 0.f, 0.f, 0.f);
    int j = b0;
    for (; j + 4 <= b1; j += 4) {
        int s0 = sSrc[j], s1 = sSrc[j + 1], s2 = sSrc[j + 2], s3 = sSrc[j + 3];
        float w0 = alpha[(size_t)j * 4 + hd];
        float w1 = alpha[(size_t)(j + 1) * 4 + hd];
        float w2 = alpha[(size_t)(j + 2) * 4 + hd];
        float w3 = alpha[(size_t)(j + 3) * 4 + hd];
        float4 h0 = h4[(size_t)s0 * 32 + lane];
        float4 h1 = h4[(size_t)s1 * 32 + lane];
        float4 h2 = h4[(size_t)s2 * 32 + lane];
        float4 h3 = h4[(size_t)s3 * 32 + lane];
        acc.x = fmaf(w0, h0.x, acc.x); acc.y = fmaf(w0, h0.y, acc.y);
        acc.z = fmaf(w0, h0.z, acc.z); acc.w = fmaf(w0, h0.w, acc.w);
        acc.x = fmaf(w1, h1.x, acc.x); acc.y = fmaf(w1, h1.y, acc.y);
        acc.z = fmaf(w1, h1.z, acc.z); acc.w = fmaf(w1, h1.w, acc.w);
        acc.x = fmaf(w2, h2.x, acc.x); acc.y = fmaf(w2, h2.y, acc.y);
        acc.z = fmaf(w2, h2.z, acc.z); acc.w = fmaf(w2, h2.w, acc.w);
        acc.x = fmaf(w3, h3.x, acc.x); acc.y = fmaf(w3, h3.y, acc.y);
        acc.z = fmaf(w3, h3.z, acc.z); acc.w = fmaf(w3, h3.w, acc.w);
    }
    for (; j < b1; ++j) {
        int s = sSrc[j];
        float w = alpha[(size_t)j * 4 + hd];
        float4 hv = h4[(size_t)s * 32 + lane];
        acc.x = fmaf(w, hv.x, acc.x); acc.y = fmaf(w, hv.y, acc.y);
        acc.z = fmaf(w, hv.z, acc.z); acc.w = fmaf(w, hv.w, acc.w);
    }
    float inv = 1.f / (sums[(size_t)d * 4 + hd] + 1e-16f);
    acc.x *= inv; acc.y *= inv; acc.z *= inv; acc.w *= inv;
    ((float4*)out)[(size_t)d * 32 + lane] = acc;
}

// ================= BN stats =================
__global__ __launch_bounds__(256) void k_bnstats(const float* __restrict__ x,
        double* __restrict__ sums, int N)
{
    __shared__ float r1[256], r2[256];
    int t = threadIdx.x;
    int c = t & 127;
    int half = t >> 7;
    float s1 = 0.f, s2 = 0.f;
    for (int n = blockIdx.x * 2 + half; n < N; n += gridDim.x * 2) {
        float v = x[(size_t)n * 128 + c];
        s1 += v; s2 += v * v;
    }
    r1[t] = s1; r2[t] = s2;
    __syncthreads();
    if (t < 128) {
        s1 = r1[t] + r1[t + 128];
        s2 = r2[t] + r2[t + 128];
        atomicAdd(&sums[t], (double)s1);
        atomicAdd(&sums[128 + t], (double)s2);
    }
}

__global__ __launch_bounds__(128) void k_bnscale(const double* __restrict__ sums,
        const float* __restrict__ gamma, const float* __restrict__ beta,
        float* __restrict__ scale, float* __restrict__ shift, int N)
{
    int c = threadIdx.x;
    double mu = sums[c] / (double)N;
    double var = sums[128 + c] / (double)N - mu * mu;
    if (var < 0.0) var = 0.0;
    double rs = 1.0 / sqrt(var + 1e-5);
    float sc = (float)((double)gamma[c] * rs);
    scale[c] = sc;
    shift[c] = beta[c] - (float)mu * sc;
}

// ================= pool =================
__global__ __launch_bounds__(128) void k_pool(const float* __restrict__ x,
        const int* __restrict__ batch, const float* __restrict__ scale, const float* __restrict__ shift,
        float* __restrict__ gsum, float* __restrict__ gcnt, int N)
{
    int lane = threadIdx.x & 31;
    int r = threadIdx.x >> 5;
    int n0 = blockIdx.x * 64;
    if (n0 >= N) return;
    int n1 = n0 + 64; if (n1 > N) n1 = N;
    float4 sc = ((const float4*)scale)[lane];
    float4 sh = ((const float4*)shift)[lane];
    float4 acc = make_float4(0.f, 0.f, 0.f, 0.f);
    int cnt = 0, cur = -1;
    for (int n = n0 + r; n < n1; n += 4) {
        int g = batch[n];
        if (g != cur) {
            if (cur >= 0) {
                atomicAdd(&gsum[cur * 128 + lane * 4 + 0], acc.x);
                atomicAdd(&gsum[cur * 128 + lane * 4 + 1], acc.y);
                atomicAdd(&gsum[cur * 128 + lane * 4 + 2], acc.z);
                atomicAdd(&gsum[cur * 128 + lane * 4 + 3], acc.w);
                if (lane == 0) atomicAdd(&gcnt[cur], (float)cnt);
            }
            acc = make_float4(0.f, 0.f, 0.f, 0.f); cnt = 0; cur = g;
        }
        float4 v = ((const float4*)x)[(size_t)n * 32 + lane];
        v.x = fmaf(v.x, sc.x, sh.x); v.x = v.x > 0.f ? v.x : 0.f;
        v.y = fmaf(v.y, sc.y, sh.y); v.y = v.y > 0.f ? v.y : 0.f;
        v.z = fmaf(v.z, sc.z, sh.z); v.z = v.z > 0.f ? v.z : 0.f;
        v.w = fmaf(v.w, sc.w, sh.w); v.w = v.w > 0.f ? v.w : 0.f;
        acc.x += v.x; acc.y += v.y; acc.z += v.z; acc.w += v.w;
        cnt++;
    }
    if (cur >= 0) {
        atomicAdd(&gsum[cur * 128 + lane * 4 + 0], acc.x);
        atomicAdd(&gsum[cur * 128 + lane * 4 + 1], acc.y);
        atomicAdd(&gsum[cur * 128 + lane * 4 + 2], acc.z);
        atomicAdd(&gsum[cur * 128 + lane * 4 + 3], acc.w);
        if (lane == 0) atomicAdd(&gcnt[cur], (float)cnt);
    }
}

// ================= dense head =================
__global__ __launch_bounds__(256) void k_head(const float* __restrict__ gsum, const float* __restrict__ gcnt,
        const float* __restrict__ d1W, const float* __restrict__ d1b,
        const float* __restrict__ g_d1, const float* __restrict__ b_d1,
        const float* __restrict__ d2W, const float* __restrict__ d2b,
        const float* __restrict__ g_d2, const float* __restrict__ b_d2,
        const float* __restrict__ fcW, const float* __restrict__ fcb,
        float* __restrict__ out)
{
    __shared__ float G[64 * 128];
    __shared__ float Y1[64 * 64];
    __shared__ float Y2[64 * 32];
    int t = threadIdx.x;
    for (int i = t; i < 64 * 128; i += 256) {
        int g = i >> 7;
        float cv = gcnt[g]; if (cv < 1.f) cv = 1.f;
        G[i] = gsum[i] / cv;
    }
    __syncthreads();
    for (int i = t; i < 64 * 64; i += 256) {
        int r = i >> 6, j = i & 63;
        float a = 0.f;
        for (int k = 0; k < 128; ++k) a = fmaf(G[r * 128 + k], d1W[k * 64 + j], a);
        Y1[i] = a + d1b[j];
    }
    __syncthreads();
    if (t < 64) {
        float s1 = 0.f, s2 = 0.f;
        for (int r = 0; r < 64; ++r) { float v = Y1[r * 64 + t]; s1 += v; s2 += v * v; }
        float mu = s1 / 64.f, var = s2 / 64.f - mu * mu; if (var < 0.f) var = 0.f;
        float rs = 1.0f / sqrtf(var + 1e-5f);
        float scv = g_d1[t] * rs, shv = b_d1[t] - mu * scv;
        for (int r = 0; r < 64; ++r) {
            float v = fmaf(Y1[r * 64 + t], scv, shv);
            Y1[r * 64 + t] = v > 0.f ? v : 0.f;
        }
    }
    __syncthreads();
    for (int i = t; i < 64 * 32; i += 256) {
        int r = i >> 5, j = i & 31;
        float a = 0.f;
        for (int k = 0; k < 64; ++k) a = fmaf(Y1[r * 64 + k], d2W[k * 32 + j], a);
        Y2[i] = a + d2b[j];
    }
    __syncthreads();
    if (t < 32) {
        float s1 = 0.f, s2 = 0.f;
        for (int r = 0; r < 64; ++r) { float v = Y2[r * 32 + t]; s1 += v; s2 += v * v; }
        float mu = s1 / 64.f, var = s2 / 64.f - mu * mu; if (var < 0.f) var = 0.f;
        float rs = 1.0f / sqrtf(var + 1e-5f);
        float scv = g_d2[t] * rs, shv = b_d2[t] - mu * scv;
        for (int r = 0; r < 64; ++r) {
            float v = fmaf(Y2[r * 32 + t], scv, shv);
            Y2[r * 32 + t] = v > 0.f ? v : 0.f;
        }
    }
    __syncthreads();
    {
        int r = t >> 2, j = t & 3;
        float a = 0.f;
        for (int k = 0; k < 32; ++k) a = fmaf(Y2[r * 32 + k], fcW[k * 4 + j], a);
        out[t] = a + fcb[j];
    }
}

extern "C" void kernel_launch(void* const* d_in, const int* in_sizes, int n_in,
                              void* d_out, int out_size, void* d_ws, size_t ws_size,
                              hipStream_t stream) {
    const int N = in_sizes[0] / 16;
    const int E = in_sizes[1] / 2;

    const float* x        = (const float*)d_in[0];
    const int*   ei       = (const int*)d_in[1];
    const int*   batch    = (const int*)d_in[2];
    const float* W1       = (const float*)d_in[3];
    const float* att_s1   = (const float*)d_in[5];
    const float* att_d1   = (const float*)d_in[6];
    const float* bn_g1    = (const float*)d_in[7];
    const float* bn_b1    = (const float*)d_in[8];
    const float* W2       = (const float*)d_in[9];
    const float* att_s2   = (const float*)d_in[11];
    const float* att_d2   = (const float*)d_in[12];
    const float* bn_g2    = (const float*)d_in[13];
    const float* bn_b2    = (const float*)d_in[14];
    const float* d1W      = (const float*)d_in[15];
    const float* d1b      = (const float*)d_in[16];
    const float* g_d1     = (const float*)d_in[17];
    const float* b_d1     = (const float*)d_in[18];
    const float* d2W      = (const float*)d_in[19];
    const float* d2b      = (const float*)d_in[20];
    const float* g_d2     = (const float*)d_in[21];
    const float* b_d2     = (const float*)d_in[22];
    const float* fcW      = (const float*)d_in[23];
    const float* fcb      = (const float*)d_in[24];
    float* out = (float*)d_out;

    float* ws = (float*)d_ws;
    size_t o = 0;
    float* hbuf   = ws + o;  o += (size_t)N * 128;
    float* outb   = ws + o;  o += (size_t)N * 128;
    float* as_    = ws + o;  o += (size_t)N * 4;
    float* ad_    = ws + o;  o += (size_t)N * 4;
    float* alpha  = ws + o;  o += (size_t)E * 4;
    float* sums   = ws + o;  o += (size_t)N * 4;
    float* scale1 = ws + o;  o += 128;
    float* shift1 = ws + o;  o += 128;
    float* scale2 = ws + o;  o += 128;
    float* shift2 = ws + o;  o += 128;
    size_t zoff = o;
    double* bnsum = (double*)(ws + o); o += 512;
    float* gsum   = ws + o;  o += 64 * 128;
    float* gcnt   = ws + o;  o += 64;
    int*   deg    = (int*)(ws + o); o += N;
    size_t zbytes = (o - zoff) * 4;
    int* rowPtr   = (int*)(ws + o); o += (size_t)N + 1;
    int* cursor   = (int*)(ws + o); o += N;
    int* sSrc     = (int*)(ws + o); o += E;
    int* blockSum = (int*)(ws + o); o += SCANB;
    int* blockOff = (int*)(ws + o); o += SCANB;

    hipMemsetAsync(ws + zoff, 0, zbytes, stream);

    // ---- CSR build (shared by both layers) ----
    k_hist<<<2048, 256, 0, stream>>>(ei, deg, E);
    k_scan1<<<SCANB, 256, 0, stream>>>(deg, blockSum, N);
    k_scan2<<<1, 256, 0, stream>>>(blockSum, blockOff, rowPtr + N);
    k_scan3<<<SCANB, 256, 0, stream>>>(deg, blockOff, rowPtr, cursor, N);
    k_scatter<<<2048, 256, 0, stream>>>(ei, cursor, sSrc, E);

    int gemm_grid = (N + 63) / 64;
    int alpha_grid = (N + 31) / 32;
    int agg_grid = (N + 7) / 8;

    // ---- layer 1 ----
    k_gemm<16, false><<<gemm_grid, 256, 0, stream>>>(x, W1, nullptr, nullptr,
            att_s1, att_d1, hbuf, as_, ad_, N);
    k_alpha<<<alpha_grid, 256, 0, stream>>>(rowPtr, sSrc, as_, ad_, alpha, sums, N);
    k_agg<<<agg_grid, 256, 0, stream>>>(rowPtr, sSrc, alpha, sums, hbuf, outb, N);
    k_bnstats<<<1024, 256, 0, stream>>>(outb, bnsum, N);
    k_bnscale<<<1, 128, 0, stream>>>(bnsum, bn_g1, bn_b1, scale1, shift1, N);

    hipMemsetAsync((void*)bnsum, 0, 512 * 4, stream);

    // ---- layer 2 ----
    k_gemm<128, true><<<gemm_grid, 256, 0, stream>>>(outb, W2, scale1, shift1,
            att_s2, att_d2, hbuf, as_, ad_, N);
    k_alpha<<<alpha_grid, 256, 0, stream>>>(rowPtr, sSrc, as_, ad_, alpha, sums, N);
    k_agg<<<agg_grid, 256, 0, stream>>>(rowPtr, sSrc, alpha, sums, hbuf, outb, N);
    k_bnstats<<<1024, 256, 0, stream>>>(outb, bnsum, N);
    k_bnscale<<<1, 128, 0, stream>>>(bnsum, bn_g2, bn_b2, scale2, shift2, N);

    // ---- pool + head ----
    k_pool<<<(N + 63) / 64, 128, 0, stream>>>(outb, batch, scale2, shift2, gsum, gcnt, N);
    k_head<<<1, 256, 0, stream>>>(gsum, gcnt, d1W, d1b, g_d1, b_d1,
                                  d2W, d2b, g_d2, b_d2, fcW, fcb, out);
}

// Round 5
// 567.099 us; speedup vs baseline: 7.8438x; 1.4916x over previous
//
#include <hip/hip_runtime.h>

#define HID 128
#define NG 64

__device__ __forceinline__ float lrelu(float v) { return v > 0.0f ? v : 0.2f * v; }

__device__ __forceinline__ unsigned int bf16rne(float f) {
    unsigned int u = __float_as_uint(f);
    return (u + 0x7fffu + ((u >> 16) & 1u)) >> 16;
}
__device__ __forceinline__ unsigned int packbf(float a, float b) {
    return bf16rne(a) | (bf16rne(b) << 16);
}

// ================= unified node-transform GEMM (h stored as bf16) =================
template <int K, bool BN>
__global__ __launch_bounds__(256) void k_gemm(const float* __restrict__ xin,
        const float* __restrict__ W,
        const float* __restrict__ scale, const float* __restrict__ shift,
        const float* __restrict__ attS, const float* __restrict__ attD,
        unsigned short* __restrict__ h, float* __restrict__ as_, float* __restrict__ ad_, int N)
{
    __shared__ float xs[64][K];
    constexpr int K4 = K / 4;
    int t = threadIdx.x;
    int cq = t & 31;
    int nr = t >> 5;

    float4 atS = ((const float4*)attS)[cq];
    float4 atD = ((const float4*)attD)[cq];

    for (int n0 = blockIdx.x * 64; n0 < N; n0 += gridDim.x * 64) {
        int nrem = N - n0; if (nrem > 64) nrem = 64;
        for (int idx = t; idx < 64 * K4; idx += 256) {
            int n = idx / K4, k4 = idx % K4;
            float4 v = make_float4(0.f, 0.f, 0.f, 0.f);
            if (n < nrem) {
                v = ((const float4*)(xin + (size_t)(n0 + n) * K))[k4];
                if (BN) {
                    float4 sc = ((const float4*)scale)[k4];
                    float4 sh = ((const float4*)shift)[k4];
                    v.x = fmaf(v.x, sc.x, sh.x); v.x = v.x > 0.f ? v.x : 0.f;
                    v.y = fmaf(v.y, sc.y, sh.y); v.y = v.y > 0.f ? v.y : 0.f;
                    v.z = fmaf(v.z, sc.z, sh.z); v.z = v.z > 0.f ? v.z : 0.f;
                    v.w = fmaf(v.w, sc.w, sh.w); v.w = v.w > 0.f ? v.w : 0.f;
                }
            }
            *(float4*)(&xs[n][k4 * 4]) = v;
        }
        __syncthreads();

        float4 acc[8];
#pragma unroll
        for (int j = 0; j < 8; ++j) acc[j] = make_float4(0.f, 0.f, 0.f, 0.f);

        const float4* W4 = (const float4*)W;
#pragma unroll 2
        for (int k4 = 0; k4 < K4; ++k4) {
            float4 w0 = W4[(k4 * 4 + 0) * 32 + cq];
            float4 w1 = W4[(k4 * 4 + 1) * 32 + cq];
            float4 w2 = W4[(k4 * 4 + 2) * 32 + cq];
            float4 w3 = W4[(k4 * 4 + 3) * 32 + cq];
#pragma unroll
            for (int j = 0; j < 8; ++j) {
                float4 xv = *(const float4*)(&xs[nr * 8 + j][k4 * 4]);
                acc[j].x = fmaf(xv.x, w0.x, acc[j].x);
                acc[j].y = fmaf(xv.x, w0.y, acc[j].y);
                acc[j].z = fmaf(xv.x, w0.z, acc[j].z);
                acc[j].w = fmaf(xv.x, w0.w, acc[j].w);
                acc[j].x = fmaf(xv.y, w1.x, acc[j].x);
                acc[j].y = fmaf(xv.y, w1.y, acc[j].y);
                acc[j].z = fmaf(xv.y, w1.z, acc[j].z);
                acc[j].w = fmaf(xv.y, w1.w, acc[j].w);
                acc[j].x = fmaf(xv.z, w2.x, acc[j].x);
                acc[j].y = fmaf(xv.z, w2.y, acc[j].y);
                acc[j].z = fmaf(xv.z, w2.z, acc[j].z);
                acc[j].w = fmaf(xv.z, w2.w, acc[j].w);
                acc[j].x = fmaf(xv.w, w3.x, acc[j].x);
                acc[j].y = fmaf(xv.w, w3.y, acc[j].y);
                acc[j].z = fmaf(xv.w, w3.z, acc[j].z);
                acc[j].w = fmaf(xv.w, w3.w, acc[j].w);
            }
        }

#pragma unroll
        for (int j = 0; j < 8; ++j) {
            int n = nr * 8 + j;
            bool ok = (n < nrem);
            if (ok) {
                unsigned int lo = packbf(acc[j].x, acc[j].y);
                unsigned int hi = packbf(acc[j].z, acc[j].w);
                ((uint2*)(h + (size_t)(n0 + n) * 128))[cq] = make_uint2(lo, hi);
            }
            float ps = acc[j].x * atS.x + acc[j].y * atS.y + acc[j].z * atS.z + acc[j].w * atS.w;
            float pd = acc[j].x * atD.x + acc[j].y * atD.y + acc[j].z * atD.z + acc[j].w * atD.w;
            ps += __shfl_xor(ps, 1); pd += __shfl_xor(pd, 1);
            ps += __shfl_xor(ps, 2); pd += __shfl_xor(pd, 2);
            ps += __shfl_xor(ps, 4); pd += __shfl_xor(pd, 4);
            if (ok && (cq & 7) == 0) {
                int hd = cq >> 3;
                as_[(size_t)(n0 + n) * 4 + hd] = ps;
                ad_[(size_t)(n0 + n) * 4 + hd] = pd;
            }
        }
        __syncthreads();
    }
}

// ================= CSR build: bucket radix (bucket = dst >> 8) =================
__global__ __launch_bounds__(256) void k_bhist(const int* __restrict__ ei,
        int* __restrict__ bSize, int E, int nB)
{
    __shared__ int hist[1024];
    int t = threadIdx.x;
    for (int i = t; i < nB; i += 256) hist[i] = 0;
    __syncthreads();
    int chunk = (E + gridDim.x - 1) / gridDim.x;
    int lo = blockIdx.x * chunk, hi = lo + chunk; if (hi > E) hi = E;
    for (int e = lo + t; e < hi; e += 256) atomicAdd(&hist[ei[E + e] >> 8], 1);
    __syncthreads();
    for (int i = t; i < nB; i += 256) { int c = hist[i]; if (c) atomicAdd(&bSize[i], c); }
}

__global__ __launch_bounds__(512) void k_bscan(const int* __restrict__ bSize,
        int* __restrict__ bOff, int* __restrict__ bCur, int nB)
{
    __shared__ int part[512];
    int t = threadIdx.x;
    part[t] = (t < nB) ? bSize[t] : 0;
    __syncthreads();
    for (int off = 1; off < 512; off <<= 1) {
        int u = (t >= off) ? part[t - off] : 0;
        __syncthreads();
        part[t] += u;
        __syncthreads();
    }
    int ex = (t == 0) ? 0 : part[t - 1];
    if (t < nB) { bOff[t] = ex; bCur[t] = ex; }
    if (t == nB - 1) bOff[nB] = part[t];
}

__global__ __launch_bounds__(256) void k_part(const int* __restrict__ ei,
        int* __restrict__ bCur, unsigned long long* __restrict__ bucketBuf, int E, int nB)
{
    __shared__ int hist[1024];
    __shared__ int base[1024];
    int t = threadIdx.x;
    int chunk = (E + gridDim.x - 1) / gridDim.x;
    int lo = blockIdx.x * chunk, hi = lo + chunk; if (hi > E) hi = E;
    for (int i = t; i < nB; i += 256) hist[i] = 0;
    __syncthreads();
    for (int e = lo + t; e < hi; e += 256) atomicAdd(&hist[ei[E + e] >> 8], 1);
    __syncthreads();
    for (int i = t; i < nB; i += 256) {
        int c = hist[i];
        base[i] = c ? atomicAdd(&bCur[i], c) : 0;
        hist[i] = 0;
    }
    __syncthreads();
    for (int e = lo + t; e < hi; e += 256) {
        int s = ei[e], d = ei[E + e];
        int b = d >> 8;
        int pos = base[b] + atomicAdd(&hist[b], 1);
        bucketBuf[pos] = ((unsigned long long)(unsigned)d << 32) | (unsigned)s;
    }
}

// block per bucket: local hist/scan -> rowPtr, then LDS scatter -> coalesced sSrc
__global__ __launch_bounds__(256) void k_build(const unsigned long long* __restrict__ bucketBuf,
        const int* __restrict__ bOff, int* __restrict__ rowPtr, int* __restrict__ sSrc, int N)
{
    __shared__ int lhist[256];
    __shared__ int sOut[8192];
    int b = blockIdx.x;
    int dlo = b << 8;
    int dhi = dlo + 256; if (dhi > N) dhi = N;
    int base = bOff[b], end = bOff[b + 1];
    int sz = end - base;
    int t = threadIdx.x;
    lhist[t] = 0;
    __syncthreads();
    for (int i = t; i < sz; i += 256) {
        int d = (int)(bucketBuf[base + i] >> 32);
        atomicAdd(&lhist[d - dlo], 1);
    }
    __syncthreads();
    for (int off = 1; off < 256; off <<= 1) {
        int u = (t >= off) ? lhist[t - off] : 0;
        __syncthreads();
        lhist[t] += u;
        __syncthreads();
    }
    int pfx = (t == 0) ? 0 : lhist[t - 1];
    if (dlo + t < dhi) rowPtr[dlo + t] = base + pfx;
    if (t == 0 && dhi == N) rowPtr[N] = end;
    __syncthreads();
    lhist[t] = pfx;
    __syncthreads();
    if (sz <= 8192) {
        for (int i = t; i < sz; i += 256) {
            unsigned long long p = bucketBuf[base + i];
            int d = (int)(p >> 32), s = (int)(p & 0xffffffffu);
            int pos = atomicAdd(&lhist[d - dlo], 1);
            sOut[pos] = s;
        }
        __syncthreads();
        for (int i = t; i < sz; i += 256) sSrc[base + i] = sOut[i];
    } else {
        for (int i = t; i < sz; i += 256) {
            unsigned long long p = bucketBuf[base + i];
            int d = (int)(p >> 32), s = (int)(p & 0xffffffffu);
            int pos = atomicAdd(&lhist[d - dlo], 1);
            sSrc[base + pos] = s;
        }
    }
}

// ================= attention weights =================
__global__ __launch_bounds__(256) void k_alpha(const int* __restrict__ rowPtr,
        const int* __restrict__ sSrc,
        const float* __restrict__ as_, const float* __restrict__ ad_,
        float* __restrict__ alpha, float* __restrict__ sums, int N)
{
    int t = threadIdx.x;
    int lane8 = t & 7;
    int d = blockIdx.x * 32 + (t >> 3);
    if (d >= N) return;
    int b0 = rowPtr[d], b1 = rowPtr[d + 1];
    float4 adv = ((const float4*)ad_)[d];

    float4 m = make_float4(-3.4e38f, -3.4e38f, -3.4e38f, -3.4e38f);
    for (int j = b0 + lane8; j < b1; j += 8) {
        int s = sSrc[j];
        float4 a = ((const float4*)as_)[s];
        m.x = fmaxf(m.x, lrelu(a.x + adv.x));
        m.y = fmaxf(m.y, lrelu(a.y + adv.y));
        m.z = fmaxf(m.z, lrelu(a.z + adv.z));
        m.w = fmaxf(m.w, lrelu(a.w + adv.w));
    }
#pragma unroll
    for (int off = 1; off < 8; off <<= 1) {
        m.x = fmaxf(m.x, __shfl_xor(m.x, off));
        m.y = fmaxf(m.y, __shfl_xor(m.y, off));
        m.z = fmaxf(m.z, __shfl_xor(m.z, off));
        m.w = fmaxf(m.w, __shfl_xor(m.w, off));
    }
    float4 sum = make_float4(0.f, 0.f, 0.f, 0.f);
    for (int j = b0 + lane8; j < b1; j += 8) {
        int s = sSrc[j];
        float4 a = ((const float4*)as_)[s];
        float4 w;
        w.x = __expf(lrelu(a.x + adv.x) - m.x);
        w.y = __expf(lrelu(a.y + adv.y) - m.y);
        w.z = __expf(lrelu(a.z + adv.z) - m.z);
        w.w = __expf(lrelu(a.w + adv.w) - m.w);
        ((float4*)alpha)[j] = w;
        sum.x += w.x; sum.y += w.y; sum.z += w.z; sum.w += w.w;
    }
#pragma unroll
    for (int off = 1; off < 8; off <<= 1) {
        sum.x += __shfl_xor(sum.x, off);
        sum.y += __shfl_xor(sum.y, off);
        sum.z += __shfl_xor(sum.z, off);
        sum.w += __shfl_xor(sum.w, off);
    }
    if (lane8 == 0) ((float4*)sums)[d] = sum;
}

// ================= CSR SpMM aggregation (bf16 h gather) =================
__global__ __launch_bounds__(256) void k_agg(const int* __restrict__ rowPtr,
        const int* __restrict__ sSrc,
        const float* __restrict__ alpha, const float* __restrict__ sums,
        const unsigned short* __restrict__ h, float* __restrict__ out, int N)
{
    int t = threadIdx.x;
    int lane = t & 31;
    int d = blockIdx.x * 8 + (t >> 5);
    if (d >= N) return;
    int hd = lane >> 3;
    int b0 = rowPtr[d], b1 = rowPtr[d + 1];
    const uint2* h2 = (const uint2*)h;

    float4 acc = make_float4(0.f, 0.f, 0.f, 0.f);
    int j = b0;
    for (; j + 4 <= b1; j += 4) {
        int s0 = sSrc[j], s1 = sSrc[j + 1], s2 = sSrc[j + 2], s3 = sSrc[j + 3];
        float w0 = alpha[(size_t)j * 4 + hd];
        float w1 = alpha[(size_t)(j + 1) * 4 + hd];
        float w2 = alpha[(size_t)(j + 2) * 4 + hd];
        float w3 = alpha[(size_t)(j + 3) * 4 + hd];
        uint2 u0 = h2[(size_t)s0 * 32 + lane];
        uint2 u1 = h2[(size_t)s1 * 32 + lane];
        uint2 u2 = h2[(size_t)s2 * 32 + lane];
        uint2 u3 = h2[(size_t)s3 * 32 + lane];
        acc.x = fmaf(w0, __uint_as_float(u0.x << 16), acc.x);
        acc.y = fmaf(w0, __uint_as_float(u0.x & 0xffff0000u), acc.y);
        acc.z = fmaf(w0, __uint_as_float(u0.y << 16), acc.z);
        acc.w = fmaf(w0, __uint_as_float(u0.y & 0xffff0000u), acc.w);
        acc.x = fmaf(w1, __uint_as_float(u1.x << 16), acc.x);
        acc.y = fmaf(w1, __uint_as_float(u1.x & 0xffff0000u), acc.y);
        acc.z = fmaf(w1, __uint_as_float(u1.y << 16), acc.z);
        acc.w = fmaf(w1, __uint_as_float(u1.y & 0xffff0000u), acc.w);
        acc.x = fmaf(w2, __uint_as_float(u2.x << 16), acc.x);
        acc.y = fmaf(w2, __uint_as_float(u2.x & 0xffff0000u), acc.y);
        acc.z = fmaf(w2, __uint_as_float(u2.y << 16), acc.z);
        acc.w = fmaf(w2, __uint_as_float(u2.y & 0xffff0000u), acc.w);
        acc.x = fmaf(w3, __uint_as_float(u3.x << 16), acc.x);
        acc.y = fmaf(w3, __uint_as_float(u3.x & 0xffff0000u), acc.y);
        acc.z = fmaf(w3, __uint_as_float(u3.y << 16), acc.z);
        acc.w = fmaf(w3, __uint_as_float(u3.y & 0xffff0000u), acc.w);
    }
    for (; j < b1; ++j) {
        int s = sSrc[j];
        float w = alpha[(size_t)j * 4 + hd];
        uint2 u = h2[(size_t)s * 32 + lane];
        acc.x = fmaf(w, __uint_as_float(u.x << 16), acc.x);
        acc.y = fmaf(w, __uint_as_float(u.x & 0xffff0000u), acc.y);
        acc.z = fmaf(w, __uint_as_float(u.y << 16), acc.z);
        acc.w = fmaf(w, __uint_as_float(u.y & 0xffff0000u), acc.w);
    }
    float inv = 1.f / (sums[(size_t)d * 4 + hd] + 1e-16f);
    acc.x *= inv; acc.y *= inv; acc.z *= inv; acc.w *= inv;
    ((float4*)out)[(size_t)d * 32 + lane] = acc;
}

// ================= BN stats =================
__global__ __launch_bounds__(256) void k_bnstats(const float* __restrict__ x,
        double* __restrict__ sums, int N)
{
    __shared__ float r1[256], r2[256];
    int t = threadIdx.x;
    int c = t & 127;
    int half = t >> 7;
    float s1 = 0.f, s2 = 0.f;
    for (int n = blockIdx.x * 2 + half; n < N; n += gridDim.x * 2) {
        float v = x[(size_t)n * 128 + c];
        s1 += v; s2 += v * v;
    }
    r1[t] = s1; r2[t] = s2;
    __syncthreads();
    if (t < 128) {
        s1 = r1[t] + r1[t + 128];
        s2 = r2[t] + r2[t + 128];
        atomicAdd(&sums[t], (double)s1);
        atomicAdd(&sums[128 + t], (double)s2);
    }
}

__global__ __launch_bounds__(128) void k_bnscale(const double* __restrict__ sums,
        const float* __restrict__ gamma, const float* __restrict__ beta,
        float* __restrict__ scale, float* __restrict__ shift, int N)
{
    int c = threadIdx.x;
    double mu = sums[c] / (double)N;
    double var = sums[128 + c] / (double)N - mu * mu;
    if (var < 0.0) var = 0.0;
    double rs = 1.0 / sqrt(var + 1e-5);
    float sc = (float)((double)gamma[c] * rs);
    scale[c] = sc;
    shift[c] = beta[c] - (float)mu * sc;
}

// ================= pool =================
__global__ __launch_bounds__(128) void k_pool(const float* __restrict__ x,
        const int* __restrict__ batch, const float* __restrict__ scale, const float* __restrict__ shift,
        float* __restrict__ gsum, float* __restrict__ gcnt, int N)
{
    int lane = threadIdx.x & 31;
    int r = threadIdx.x >> 5;
    int n0 = blockIdx.x * 64;
    if (n0 >= N) return;
    int n1 = n0 + 64; if (n1 > N) n1 = N;
    float4 sc = ((const float4*)scale)[lane];
    float4 sh = ((const float4*)shift)[lane];
    float4 acc = make_float4(0.f, 0.f, 0.f, 0.f);
    int cnt = 0, cur = -1;
    for (int n = n0 + r; n < n1; n += 4) {
        int g = batch[n];
        if (g != cur) {
            if (cur >= 0) {
                atomicAdd(&gsum[cur * 128 + lane * 4 + 0], acc.x);
                atomicAdd(&gsum[cur * 128 + lane * 4 + 1], acc.y);
                atomicAdd(&gsum[cur * 128 + lane * 4 + 2], acc.z);
                atomicAdd(&gsum[cur * 128 + lane * 4 + 3], acc.w);
                if (lane == 0) atomicAdd(&gcnt[cur], (float)cnt);
            }
            acc = make_float4(0.f, 0.f, 0.f, 0.f); cnt = 0; cur = g;
        }
        float4 v = ((const float4*)x)[(size_t)n * 32 + lane];
        v.x = fmaf(v.x, sc.x, sh.x); v.x = v.x > 0.f ? v.x : 0.f;
        v.y = fmaf(v.y, sc.y, sh.y); v.y = v.y > 0.f ? v.y : 0.f;
        v.z = fmaf(v.z, sc.z, sh.z); v.z = v.z > 0.f ? v.z : 0.f;
        v.w = fmaf(v.w, sc.w, sh.w); v.w = v.w > 0.f ? v.w : 0.f;
        acc.x += v.x; acc.y += v.y; acc.z += v.z; acc.w += v.w;
        cnt++;
    }
    if (cur >= 0) {
        atomicAdd(&gsum[cur * 128 + lane * 4 + 0], acc.x);
        atomicAdd(&gsum[cur * 128 + lane * 4 + 1], acc.y);
        atomicAdd(&gsum[cur * 128 + lane * 4 + 2], acc.z);
        atomicAdd(&gsum[cur * 128 + lane * 4 + 3], acc.w);
        if (lane == 0) atomicAdd(&gcnt[cur], (float)cnt);
    }
}

// ================= dense head =================
__global__ __launch_bounds__(256) void k_head(const float* __restrict__ gsum, const float* __restrict__ gcnt,
        const float* __restrict__ d1W, const float* __restrict__ d1b,
        const float* __restrict__ g_d1, const float* __restrict__ b_d1,
        const float* __restrict__ d2W, const float* __restrict__ d2b,
        const float* __restrict__ g_d2, const float* __restrict__ b_d2,
        const float* __restrict__ fcW, const float* __restrict__ fcb,
        float* __restrict__ out)
{
    __shared__ float G[64 * 128];
    __shared__ float Y1[64 * 64];
    __shared__ float Y2[64 * 32];
    int t = threadIdx.x;
    for (int i = t; i < 64 * 128; i += 256) {
        int g = i >> 7;
        float cv = gcnt[g]; if (cv < 1.f) cv = 1.f;
        G[i] = gsum[i] / cv;
    }
    __syncthreads();
    for (int i = t; i < 64 * 64; i += 256) {
        int r = i >> 6, j = i & 63;
        float a = 0.f;
        for (int k = 0; k < 128; ++k) a = fmaf(G[r * 128 + k], d1W[k * 64 + j], a);
        Y1[i] = a + d1b[j];
    }
    __syncthreads();
    if (t < 64) {
        float s1 = 0.f, s2 = 0.f;
        for (int r = 0; r < 64; ++r) { float v = Y1[r * 64 + t]; s1 += v; s2 += v * v; }
        float mu = s1 / 64.f, var = s2 / 64.f - mu * mu; if (var < 0.f) var = 0.f;
        float rs = 1.0f / sqrtf(var + 1e-5f);
        float scv = g_d1[t] * rs, shv = b_d1[t] - mu * scv;
        for (int r = 0; r < 64; ++r) {
            float v = fmaf(Y1[r * 64 + t], scv, shv);
            Y1[r * 64 + t] = v > 0.f ? v : 0.f;
        }
    }
    __syncthreads();
    for (int i = t; i < 64 * 32; i += 256) {
        int r = i >> 5, j = i & 31;
        float a = 0.f;
        for (int k = 0; k < 64; ++k) a = fmaf(Y1[r * 64 + k], d2W[k * 32 + j], a);
        Y2[i] = a + d2b[j];
    }
    __syncthreads();
    if (t < 32) {
        float s1 = 0.f, s2 = 0.f;
        for (int r = 0; r < 64; ++r) { float v = Y2[r * 32 + t]; s1 += v; s2 += v * v; }
        float mu = s1 / 64.f, var = s2 / 64.f - mu * mu; if (var < 0.f) var = 0.f;
        float rs = 1.0f / sqrtf(var + 1e-5f);
        float scv = g_d2[t] * rs, shv = b_d2[t] - mu * scv;
        for (int r = 0; r < 64; ++r) {
            float v = fmaf(Y2[r * 32 + t], scv, shv);
            Y2[r * 32 + t] = v > 0.f ? v : 0.f;
        }
    }
    __syncthreads();
    {
        int r = t >> 2, j = t & 3;
        float a = 0.f;
        for (int k = 0; k < 32; ++k) a = fmaf(Y2[r * 32 + k], fcW[k * 4 + j], a);
        out[t] = a + fcb[j];
    }
}

extern "C" void kernel_launch(void* const* d_in, const int* in_sizes, int n_in,
                              void* d_out, int out_size, void* d_ws, size_t ws_size,
                              hipStream_t stream) {
    const int N = in_sizes[0] / 16;
    const int E = in_sizes[1] / 2;
    const int nB = (N + 255) >> 8;

    const float* x        = (const float*)d_in[0];
    const int*   ei       = (const int*)d_in[1];
    const int*   batch    = (const int*)d_in[2];
    const float* W1       = (const float*)d_in[3];
    const float* att_s1   = (const float*)d_in[5];
    const float* att_d1   = (const float*)d_in[6];
    const float* bn_g1    = (const float*)d_in[7];
    const float* bn_b1    = (const float*)d_in[8];
    const float* W2       = (const float*)d_in[9];
    const float* att_s2   = (const float*)d_in[11];
    const float* att_d2   = (const float*)d_in[12];
    const float* bn_g2    = (const float*)d_in[13];
    const float* bn_b2    = (const float*)d_in[14];
    const float* d1W      = (const float*)d_in[15];
    const float* d1b      = (const float*)d_in[16];
    const float* g_d1     = (const float*)d_in[17];
    const float* b_d1     = (const float*)d_in[18];
    const float* d2W      = (const float*)d_in[19];
    const float* d2b      = (const float*)d_in[20];
    const float* g_d2     = (const float*)d_in[21];
    const float* b_d2     = (const float*)d_in[22];
    const float* fcW      = (const float*)d_in[23];
    const float* fcb      = (const float*)d_in[24];
    float* out = (float*)d_out;

    float* ws = (float*)d_ws;
    size_t o = 0;
    unsigned short* hbuf = (unsigned short*)(ws + o); o += (size_t)N * 64;  // N*128 bf16
    float* outb   = ws + o;  o += (size_t)N * 128;
    float* as_    = ws + o;  o += (size_t)N * 4;
    float* ad_    = ws + o;  o += (size_t)N * 4;
    float* alpha  = ws + o;  o += (size_t)E * 4;
    float* sums   = ws + o;  o += (size_t)N * 4;
    float* scale1 = ws + o;  o += 128;
    float* shift1 = ws + o;  o += 128;
    float* scale2 = ws + o;  o += 128;
    float* shift2 = ws + o;  o += 128;
    // ---- zero region (one memset): bnsum, gsum, gcnt, bSize ----
    size_t zoff = o;
    double* bnsum = (double*)(ws + o); o += 512;
    float* gsum   = ws + o;  o += 64 * 128;
    float* gcnt   = ws + o;  o += 64;
    int*   bSize  = (int*)(ws + o); o += 1024;
    size_t zbytes = (o - zoff) * 4;
    int* rowPtr   = (int*)(ws + o); o += (size_t)N + 1;
    int* sSrc     = (int*)(ws + o); o += E;
    int* bOff     = (int*)(ws + o); o += 1025;
    int* bCur     = (int*)(ws + o); o += 1024;
    o = (o + 1) & ~(size_t)1;  // 8B align
    unsigned long long* bucketBuf = (unsigned long long*)(ws + o); o += (size_t)E * 2;

    hipMemsetAsync(ws + zoff, 0, zbytes, stream);

    // ---- CSR build (bucket radix, shared by both layers) ----
    k_bhist<<<256, 256, 0, stream>>>(ei, bSize, E, nB);
    k_bscan<<<1, 512, 0, stream>>>(bSize, bOff, bCur, nB);
    k_part<<<256, 256, 0, stream>>>(ei, bCur, bucketBuf, E, nB);
    k_build<<<nB, 256, 0, stream>>>(bucketBuf, bOff, rowPtr, sSrc, N);

    int gemm_grid = (N + 63) / 64;
    int alpha_grid = (N + 31) / 32;
    int agg_grid = (N + 7) / 8;

    // ---- layer 1 ----
    k_gemm<16, false><<<gemm_grid, 256, 0, stream>>>(x, W1, nullptr, nullptr,
            att_s1, att_d1, hbuf, as_, ad_, N);
    k_alpha<<<alpha_grid, 256, 0, stream>>>(rowPtr, sSrc, as_, ad_, alpha, sums, N);
    k_agg<<<agg_grid, 256, 0, stream>>>(rowPtr, sSrc, alpha, sums, hbuf, outb, N);
    k_bnstats<<<1024, 256, 0, stream>>>(outb, bnsum, N);
    k_bnscale<<<1, 128, 0, stream>>>(bnsum, bn_g1, bn_b1, scale1, shift1, N);

    hipMemsetAsync((void*)bnsum, 0, 512 * 4, stream);

    // ---- layer 2 ----
    k_gemm<128, true><<<gemm_grid, 256, 0, stream>>>(outb, W2, scale1, shift1,
            att_s2, att_d2, hbuf, as_, ad_, N);
    k_alpha<<<alpha_grid, 256, 0, stream>>>(rowPtr, sSrc, as_, ad_, alpha, sums, N);
    k_agg<<<agg_grid, 256, 0, stream>>>(rowPtr, sSrc, alpha, sums, hbuf, outb, N);
    k_bnstats<<<1024, 256, 0, stream>>>(outb, bnsum, N);
    k_bnscale<<<1, 128, 0, stream>>>(bnsum, bn_g2, bn_b2, scale2, shift2, N);

    // ---- pool + head ----
    k_pool<<<(N + 63) / 64, 128, 0, stream>>>(outb, batch, scale2, shift2, gsum, gcnt, N);
    k_head<<<1, 256, 0, stream>>>(gsum, gcnt, d1W, d1b, g_d1, b_d1,
                                  d2W, d2b, g_d2, b_d2, fcW, fcb, out);
}

// Round 7
// 540.780 us; speedup vs baseline: 8.2255x; 1.0487x over previous
//
#include <hip/hip_runtime.h>

#define HID 128
#define NG 64

__device__ __forceinline__ float lrelu(float v) { return v > 0.0f ? v : 0.2f * v; }

__device__ __forceinline__ unsigned int bf16rne(float f) {
    unsigned int u = __float_as_uint(f);
    return (u + 0x7fffu + ((u >> 16) & 1u)) >> 16;
}
__device__ __forceinline__ unsigned int packbf(float a, float b) {
    return bf16rne(a) | (bf16rne(b) << 16);
}

// ================= unified node-transform GEMM (h stored as bf16) =================
template <int K, bool BN>
__global__ __launch_bounds__(256) void k_gemm(const float* __restrict__ xin,
        const float* __restrict__ W,
        const float* __restrict__ scale, const float* __restrict__ shift,
        const float* __restrict__ attS, const float* __restrict__ attD,
        unsigned short* __restrict__ h, float* __restrict__ as_, float* __restrict__ ad_, int N)
{
    __shared__ float xs[64][K];
    constexpr int K4 = K / 4;
    int t = threadIdx.x;
    int cq = t & 31;
    int nr = t >> 5;

    float4 atS = ((const float4*)attS)[cq];
    float4 atD = ((const float4*)attD)[cq];

    for (int n0 = blockIdx.x * 64; n0 < N; n0 += gridDim.x * 64) {
        int nrem = N - n0; if (nrem > 64) nrem = 64;
        for (int idx = t; idx < 64 * K4; idx += 256) {
            int n = idx / K4, k4 = idx % K4;
            float4 v = make_float4(0.f, 0.f, 0.f, 0.f);
            if (n < nrem) {
                v = ((const float4*)(xin + (size_t)(n0 + n) * K))[k4];
                if (BN) {
                    float4 sc = ((const float4*)scale)[k4];
                    float4 sh = ((const float4*)shift)[k4];
                    v.x = fmaf(v.x, sc.x, sh.x); v.x = v.x > 0.f ? v.x : 0.f;
                    v.y = fmaf(v.y, sc.y, sh.y); v.y = v.y > 0.f ? v.y : 0.f;
                    v.z = fmaf(v.z, sc.z, sh.z); v.z = v.z > 0.f ? v.z : 0.f;
                    v.w = fmaf(v.w, sc.w, sh.w); v.w = v.w > 0.f ? v.w : 0.f;
                }
            }
            *(float4*)(&xs[n][k4 * 4]) = v;
        }
        __syncthreads();

        float4 acc[8];
#pragma unroll
        for (int j = 0; j < 8; ++j) acc[j] = make_float4(0.f, 0.f, 0.f, 0.f);

        const float4* W4 = (const float4*)W;
#pragma unroll 2
        for (int k4 = 0; k4 < K4; ++k4) {
            float4 w0 = W4[(k4 * 4 + 0) * 32 + cq];
            float4 w1 = W4[(k4 * 4 + 1) * 32 + cq];
            float4 w2 = W4[(k4 * 4 + 2) * 32 + cq];
            float4 w3 = W4[(k4 * 4 + 3) * 32 + cq];
#pragma unroll
            for (int j = 0; j < 8; ++j) {
                float4 xv = *(const float4*)(&xs[nr * 8 + j][k4 * 4]);
                acc[j].x = fmaf(xv.x, w0.x, acc[j].x);
                acc[j].y = fmaf(xv.x, w0.y, acc[j].y);
                acc[j].z = fmaf(xv.x, w0.z, acc[j].z);
                acc[j].w = fmaf(xv.x, w0.w, acc[j].w);
                acc[j].x = fmaf(xv.y, w1.x, acc[j].x);
                acc[j].y = fmaf(xv.y, w1.y, acc[j].y);
                acc[j].z = fmaf(xv.y, w1.z, acc[j].z);
                acc[j].w = fmaf(xv.y, w1.w, acc[j].w);
                acc[j].x = fmaf(xv.z, w2.x, acc[j].x);
                acc[j].y = fmaf(xv.z, w2.y, acc[j].y);
                acc[j].z = fmaf(xv.z, w2.z, acc[j].z);
                acc[j].w = fmaf(xv.z, w2.w, acc[j].w);
                acc[j].x = fmaf(xv.w, w3.x, acc[j].x);
                acc[j].y = fmaf(xv.w, w3.y, acc[j].y);
                acc[j].z = fmaf(xv.w, w3.z, acc[j].z);
                acc[j].w = fmaf(xv.w, w3.w, acc[j].w);
            }
        }

#pragma unroll
        for (int j = 0; j < 8; ++j) {
            int n = nr * 8 + j;
            bool ok = (n < nrem);
            if (ok) {
                unsigned int lo = packbf(acc[j].x, acc[j].y);
                unsigned int hi = packbf(acc[j].z, acc[j].w);
                ((uint2*)(h + (size_t)(n0 + n) * 128))[cq] = make_uint2(lo, hi);
            }
            float ps = acc[j].x * atS.x + acc[j].y * atS.y + acc[j].z * atS.z + acc[j].w * atS.w;
            float pd = acc[j].x * atD.x + acc[j].y * atD.y + acc[j].z * atD.z + acc[j].w * atD.w;
            ps += __shfl_xor(ps, 1); pd += __shfl_xor(pd, 1);
            ps += __shfl_xor(ps, 2); pd += __shfl_xor(pd, 2);
            ps += __shfl_xor(ps, 4); pd += __shfl_xor(pd, 4);
            if (ok && (cq & 7) == 0) {
                int hd = cq >> 3;
                as_[(size_t)(n0 + n) * 4 + hd] = ps;
                ad_[(size_t)(n0 + n) * 4 + hd] = pd;
            }
        }
        __syncthreads();
    }
}

// ================= CSR build: bucket radix (bucket = dst >> 8), packed 4B =================
__global__ __launch_bounds__(256) void k_bhist(const int* __restrict__ ei,
        int* __restrict__ bSize, int E, int nB)
{
    __shared__ int hist[1024];
    int t = threadIdx.x;
    for (int i = t; i < nB; i += 256) hist[i] = 0;
    __syncthreads();
    int chunk = (E + gridDim.x - 1) / gridDim.x;
    int lo = blockIdx.x * chunk, hi = lo + chunk; if (hi > E) hi = E;
    for (int e = lo + t; e < hi; e += 256) atomicAdd(&hist[ei[E + e] >> 8], 1);
    __syncthreads();
    for (int i = t; i < nB; i += 256) { int c = hist[i]; if (c) atomicAdd(&bSize[i], c); }
}

__global__ __launch_bounds__(512) void k_bscan(const int* __restrict__ bSize,
        int* __restrict__ bOff, int* __restrict__ bCur, int nB)
{
    __shared__ int part[512];
    int t = threadIdx.x;
    part[t] = (t < nB) ? bSize[t] : 0;
    __syncthreads();
    for (int off = 1; off < 512; off <<= 1) {
        int u = (t >= off) ? part[t - off] : 0;
        __syncthreads();
        part[t] += u;
        __syncthreads();
    }
    int ex = (t == 0) ? 0 : part[t - 1];
    if (t < nB) { bOff[t] = ex; bCur[t] = ex; }
    if (t == nB - 1) bOff[nB] = part[t];
}

__global__ __launch_bounds__(256) void k_part(const int* __restrict__ ei,
        int* __restrict__ bCur, unsigned int* __restrict__ bucketBuf, int E, int nB)
{
    __shared__ int hist[1024];
    __shared__ int base[1024];
    int t = threadIdx.x;
    int chunk = (E + gridDim.x - 1) / gridDim.x;
    int lo = blockIdx.x * chunk, hi = lo + chunk; if (hi > E) hi = E;
    for (int i = t; i < nB; i += 256) hist[i] = 0;
    __syncthreads();
    for (int e = lo + t; e < hi; e += 256) atomicAdd(&hist[ei[E + e] >> 8], 1);
    __syncthreads();
    for (int i = t; i < nB; i += 256) {
        int c = hist[i];
        base[i] = c ? atomicAdd(&bCur[i], c) : 0;
        hist[i] = 0;
    }
    __syncthreads();
    for (int e = lo + t; e < hi; e += 256) {
        int s = ei[e], d = ei[E + e];
        int b = d >> 8;
        int pos = base[b] + atomicAdd(&hist[b], 1);
        bucketBuf[pos] = ((unsigned)(d & 255) << 24) | (unsigned)s;  // N < 2^24
    }
}

// block per bucket: local hist/scan -> rowPtr, then LDS scatter -> coalesced sSrc
__global__ __launch_bounds__(256) void k_build(const unsigned int* __restrict__ bucketBuf,
        const int* __restrict__ bOff, int* __restrict__ rowPtr, int* __restrict__ sSrc, int N)
{
    __shared__ int lhist[256];
    __shared__ int sOut[8192];
    int b = blockIdx.x;
    int dlo = b << 8;
    int dhi = dlo + 256; if (dhi > N) dhi = N;
    int base = bOff[b], end = bOff[b + 1];
    int sz = end - base;
    int t = threadIdx.x;
    lhist[t] = 0;
    __syncthreads();
    for (int i = t; i < sz; i += 256) {
        atomicAdd(&lhist[bucketBuf[base + i] >> 24], 1);
    }
    __syncthreads();
    for (int off = 1; off < 256; off <<= 1) {
        int u = (t >= off) ? lhist[t - off] : 0;
        __syncthreads();
        lhist[t] += u;
        __syncthreads();
    }
    int pfx = (t == 0) ? 0 : lhist[t - 1];
    if (dlo + t < dhi) rowPtr[dlo + t] = base + pfx;
    if (t == 0 && dhi == N) rowPtr[N] = end;
    __syncthreads();
    lhist[t] = pfx;
    __syncthreads();
    if (sz <= 8192) {
        for (int i = t; i < sz; i += 256) {
            unsigned int p = bucketBuf[base + i];
            int pos = atomicAdd(&lhist[p >> 24], 1);
            sOut[pos] = (int)(p & 0xffffffu);
        }
        __syncthreads();
        for (int i = t; i < sz; i += 256) sSrc[base + i] = sOut[i];
    } else {
        for (int i = t; i < sz; i += 256) {
            unsigned int p = bucketBuf[base + i];
            int pos = atomicAdd(&lhist[p >> 24], 1);
            sSrc[base + pos] = (int)(p & 0xffffffu);
        }
    }
}

// ================= fused softmax + CSR SpMM aggregation =================
// 32 threads per dst; pass 1: cooperative per-head exp-sum (no max shift —
// logits bounded, exp safe in f32, alpha identical after normalization);
// pass 2: recompute w inline (as_ table is L2-hot), accumulate w*h, scale 1/sum.
__global__ __launch_bounds__(256) void k_agg(const int* __restrict__ rowPtr,
        const int* __restrict__ sSrc,
        const float* __restrict__ as_, const float* __restrict__ ad_,
        const unsigned short* __restrict__ h, float* __restrict__ out, int N)
{
    int t = threadIdx.x;
    int lane = t & 31;
    int d = blockIdx.x * 8 + (t >> 5);
    if (d >= N) return;
    int hd = lane >> 3;
    int b0 = rowPtr[d], b1 = rowPtr[d + 1];
    float4 adv = ((const float4*)ad_)[d];

    // pass 1: per-head sums of exp(lrelu(as+ad)) over this dst's edges
    float4 sm = make_float4(0.f, 0.f, 0.f, 0.f);
    for (int j = b0 + lane; j < b1; j += 32) {
        int s = sSrc[j];
        float4 a = ((const float4*)as_)[s];
        sm.x += __expf(lrelu(a.x + adv.x));
        sm.y += __expf(lrelu(a.y + adv.y));
        sm.z += __expf(lrelu(a.z + adv.z));
        sm.w += __expf(lrelu(a.w + adv.w));
    }
#pragma unroll
    for (int off = 1; off < 32; off <<= 1) {
        sm.x += __shfl_xor(sm.x, off);
        sm.y += __shfl_xor(sm.y, off);
        sm.z += __shfl_xor(sm.z, off);
        sm.w += __shfl_xor(sm.w, off);
    }
    float sumh = (hd == 0) ? sm.x : (hd == 1) ? sm.y : (hd == 2) ? sm.z : sm.w;
    float inv = 1.f / (sumh + 1e-16f);
    float advh = (hd == 0) ? adv.x : (hd == 1) ? adv.y : (hd == 2) ? adv.z : adv.w;

    const uint2* h2 = (const uint2*)h;
    float4 acc = make_float4(0.f, 0.f, 0.f, 0.f);
    int j = b0;
    for (; j + 4 <= b1; j += 4) {
        int s0 = sSrc[j], s1 = sSrc[j + 1], s2 = sSrc[j + 2], s3 = sSrc[j + 3];
        float w0 = __expf(lrelu(as_[(size_t)s0 * 4 + hd] + advh));
        float w1 = __expf(lrelu(as_[(size_t)s1 * 4 + hd] + advh));
        float w2 = __expf(lrelu(as_[(size_t)s2 * 4 + hd] + advh));
        float w3 = __expf(lrelu(as_[(size_t)s3 * 4 + hd] + advh));
        uint2 u0 = h2[(size_t)s0 * 32 + lane];
        uint2 u1 = h2[(size_t)s1 * 32 + lane];
        uint2 u2 = h2[(size_t)s2 * 32 + lane];
        uint2 u3 = h2[(size_t)s3 * 32 + lane];
        acc.x = fmaf(w0, __uint_as_float(u0.x << 16), acc.x);
        acc.y = fmaf(w0, __uint_as_float(u0.x & 0xffff0000u), acc.y);
        acc.z = fmaf(w0, __uint_as_float(u0.y << 16), acc.z);
        acc.w = fmaf(w0, __uint_as_float(u0.y & 0xffff0000u), acc.w);
        acc.x = fmaf(w1, __uint_as_float(u1.x << 16), acc.x);
        acc.y = fmaf(w1, __uint_as_float(u1.x & 0xffff0000u), acc.y);
        acc.z = fmaf(w1, __uint_as_float(u1.y << 16), acc.z);
        acc.w = fmaf(w1, __uint_as_float(u1.y & 0xffff0000u), acc.w);
        acc.x = fmaf(w2, __uint_as_float(u2.x << 16), acc.x);
        acc.y = fmaf(w2, __uint_as_float(u2.x & 0xffff0000u), acc.y);
        acc.z = fmaf(w2, __uint_as_float(u2.y << 16), acc.z);
        acc.w = fmaf(w2, __uint_as_float(u2.y & 0xffff0000u), acc.w);
        acc.x = fmaf(w3, __uint_as_float(u3.x << 16), acc.x);
        acc.y = fmaf(w3, __uint_as_float(u3.x & 0xffff0000u), acc.y);
        acc.z = fmaf(w3, __uint_as_float(u3.y << 16), acc.z);
        acc.w = fmaf(w3, __uint_as_float(u3.y & 0xffff0000u), acc.w);
    }
    for (; j < b1; ++j) {
        int s = sSrc[j];
        float w = __expf(lrelu(as_[(size_t)s * 4 + hd] + advh));
        uint2 u = h2[(size_t)s * 32 + lane];
        acc.x = fmaf(w, __uint_as_float(u.x << 16), acc.x);
        acc.y = fmaf(w, __uint_as_float(u.x & 0xffff0000u), acc.y);
        acc.z = fmaf(w, __uint_as_float(u.y << 16), acc.z);
        acc.w = fmaf(w, __uint_as_float(u.y & 0xffff0000u), acc.w);
    }
    acc.x *= inv; acc.y *= inv; acc.z *= inv; acc.w *= inv;
    ((float4*)out)[(size_t)d * 32 + lane] = acc;
}

// ================= BN stats =================
__global__ __launch_bounds__(256) void k_bnstats(const float* __restrict__ x,
        double* __restrict__ sums, int N)
{
    __shared__ float r1[256], r2[256];
    int t = threadIdx.x;
    int c = t & 127;
    int half = t >> 7;
    float s1 = 0.f, s2 = 0.f;
    for (int n = blockIdx.x * 2 + half; n < N; n += gridDim.x * 2) {
        float v = x[(size_t)n * 128 + c];
        s1 += v; s2 += v * v;
    }
    r1[t] = s1; r2[t] = s2;
    __syncthreads();
    if (t < 128) {
        s1 = r1[t] + r1[t + 128];
        s2 = r2[t] + r2[t + 128];
        atomicAdd(&sums[t], (double)s1);
        atomicAdd(&sums[128 + t], (double)s2);
    }
}

__global__ __launch_bounds__(128) void k_bnscale(const double* __restrict__ sums,
        const float* __restrict__ gamma, const float* __restrict__ beta,
        float* __restrict__ scale, float* __restrict__ shift, int N)
{
    int c = threadIdx.x;
    double mu = sums[c] / (double)N;
    double var = sums[128 + c] / (double)N - mu * mu;
    if (var < 0.0) var = 0.0;
    double rs = 1.0 / sqrt(var + 1e-5);
    float sc = (float)((double)gamma[c] * rs);
    scale[c] = sc;
    shift[c] = beta[c] - (float)mu * sc;
}

// ================= pool =================
__global__ __launch_bounds__(128) void k_pool(const float* __restrict__ x,
        const int* __restrict__ batch, const float* __restrict__ scale, const float* __restrict__ shift,
        float* __restrict__ gsum, float* __restrict__ gcnt, int N)
{
    int lane = threadIdx.x & 31;
    int r = threadIdx.x >> 5;
    int n0 = blockIdx.x * 64;
    if (n0 >= N) return;
    int n1 = n0 + 64; if (n1 > N) n1 = N;
    float4 sc = ((const float4*)scale)[lane];
    float4 sh = ((const float4*)shift)[lane];
    float4 acc = make_float4(0.f, 0.f, 0.f, 0.f);
    int cnt = 0, cur = -1;
    for (int n = n0 + r; n < n1; n += 4) {
        int g = batch[n];
        if (g != cur) {
            if (cur >= 0) {
                atomicAdd(&gsum[cur * 128 + lane * 4 + 0], acc.x);
                atomicAdd(&gsum[cur * 128 + lane * 4 + 1], acc.y);
                atomicAdd(&gsum[cur * 128 + lane * 4 + 2], acc.z);
                atomicAdd(&gsum[cur * 128 + lane * 4 + 3], acc.w);
                if (lane == 0) atomicAdd(&gcnt[cur], (float)cnt);
            }
            acc = make_float4(0.f, 0.f, 0.f, 0.f); cnt = 0; cur = g;
        }
        float4 v = ((const float4*)x)[(size_t)n * 32 + lane];
        v.x = fmaf(v.x, sc.x, sh.x); v.x = v.x > 0.f ? v.x : 0.f;
        v.y = fmaf(v.y, sc.y, sh.y); v.y = v.y > 0.f ? v.y : 0.f;
        v.z = fmaf(v.z, sc.z, sh.z); v.z = v.z > 0.f ? v.z : 0.f;
        v.w = fmaf(v.w, sc.w, sh.w); v.w = v.w > 0.f ? v.w : 0.f;
        acc.x += v.x; acc.y += v.y; acc.z += v.z; acc.w += v.w;
        cnt++;
    }
    if (cur >= 0) {
        atomicAdd(&gsum[cur * 128 + lane * 4 + 0], acc.x);
        atomicAdd(&gsum[cur * 128 + lane * 4 + 1], acc.y);
        atomicAdd(&gsum[cur * 128 + lane * 4 + 2], acc.z);
        atomicAdd(&gsum[cur * 128 + lane * 4 + 3], acc.w);
        if (lane == 0) atomicAdd(&gcnt[cur], (float)cnt);
    }
}

// ================= dense head =================
__global__ __launch_bounds__(256) void k_head(const float* __restrict__ gsum, const float* __restrict__ gcnt,
        const float* __restrict__ d1W, const float* __restrict__ d1b,
        const float* __restrict__ g_d1, const float* __restrict__ b_d1,
        const float* __restrict__ d2W, const float* __restrict__ d2b,
        const float* __restrict__ g_d2, const float* __restrict__ b_d2,
        const float* __restrict__ fcW, const float* __restrict__ fcb,
        float* __restrict__ out)
{
    __shared__ float G[64 * 128];
    __shared__ float Y1[64 * 64];
    __shared__ float Y2[64 * 32];
    int t = threadIdx.x;
    for (int i = t; i < 64 * 128; i += 256) {
        int g = i >> 7;
        float cv = gcnt[g]; if (cv < 1.f) cv = 1.f;
        G[i] = gsum[i] / cv;
    }
    __syncthreads();
    for (int i = t; i < 64 * 64; i += 256) {
        int r = i >> 6, j = i & 63;
        float a = 0.f;
        for (int k = 0; k < 128; ++k) a = fmaf(G[r * 128 + k], d1W[k * 64 + j], a);
        Y1[i] = a + d1b[j];
    }
    __syncthreads();
    if (t < 64) {
        float s1 = 0.f, s2 = 0.f;
        for (int r = 0; r < 64; ++r) { float v = Y1[r * 64 + t]; s1 += v; s2 += v * v; }
        float mu = s1 / 64.f, var = s2 / 64.f - mu * mu; if (var < 0.f) var = 0.f;
        float rs = 1.0f / sqrtf(var + 1e-5f);
        float scv = g_d1[t] * rs, shv = b_d1[t] - mu * scv;
        for (int r = 0; r < 64; ++r) {
            float v = fmaf(Y1[r * 64 + t], scv, shv);
            Y1[r * 64 + t] = v > 0.f ? v : 0.f;
        }
    }
    __syncthreads();
    for (int i = t; i < 64 * 32; i += 256) {
        int r = i >> 5, j = i & 31;
        float a = 0.f;
        for (int k = 0; k < 64; ++k) a = fmaf(Y1[r * 64 + k], d2W[k * 32 + j], a);
        Y2[i] = a + d2b[j];
    }
    __syncthreads();
    if (t < 32) {
        float s1 = 0.f, s2 = 0.f;
        for (int r = 0; r < 64; ++r) { float v = Y2[r * 32 + t]; s1 += v; s2 += v * v; }
        float mu = s1 / 64.f, var = s2 / 64.f - mu * mu; if (var < 0.f) var = 0.f;
        float rs = 1.0f / sqrtf(var + 1e-5f);
        float scv = g_d2[t] * rs, shv = b_d2[t] - mu * scv;
        for (int r = 0; r < 64; ++r) {
            float v = fmaf(Y2[r * 32 + t], scv, shv);
            Y2[r * 32 + t] = v > 0.f ? v : 0.f;
        }
    }
    __syncthreads();
    {
        int r = t >> 2, j = t & 3;
        float a = 0.f;
        for (int k = 0; k < 32; ++k) a = fmaf(Y2[r * 32 + k], fcW[k * 4 + j], a);
        out[t] = a + fcb[j];
    }
}

extern "C" void kernel_launch(void* const* d_in, const int* in_sizes, int n_in,
                              void* d_out, int out_size, void* d_ws, size_t ws_size,
                              hipStream_t stream) {
    const int N = in_sizes[0] / 16;
    const int E = in_sizes[1] / 2;
    const int nB = (N + 255) >> 8;

    const float* x        = (const float*)d_in[0];
    const int*   ei       = (const int*)d_in[1];
    const int*   batch    = (const int*)d_in[2];
    const float* W1       = (const float*)d_in[3];
    const float* att_s1   = (const float*)d_in[5];
    const float* att_d1   = (const float*)d_in[6];
    const float* bn_g1    = (const float*)d_in[7];
    const float* bn_b1    = (const float*)d_in[8];
    const float* W2       = (const float*)d_in[9];
    const float* att_s2   = (const float*)d_in[11];
    const float* att_d2   = (const float*)d_in[12];
    const float* bn_g2    = (const float*)d_in[13];
    const float* bn_b2    = (const float*)d_in[14];
    const float* d1W      = (const float*)d_in[15];
    const float* d1b      = (const float*)d_in[16];
    const float* g_d1     = (const float*)d_in[17];
    const float* b_d1     = (const float*)d_in[18];
    const float* d2W      = (const float*)d_in[19];
    const float* d2b      = (const float*)d_in[20];
    const float* g_d2     = (const float*)d_in[21];
    const float* b_d2     = (const float*)d_in[22];
    const float* fcW      = (const float*)d_in[23];
    const float* fcb      = (const float*)d_in[24];
    float* out = (float*)d_out;

    float* ws = (float*)d_ws;
    size_t o = 0;
    unsigned short* hbuf = (unsigned short*)(ws + o); o += (size_t)N * 64;  // N*128 bf16
    float* outb   = ws + o;  o += (size_t)N * 128;
    float* as_    = ws + o;  o += (size_t)N * 4;
    float* ad_    = ws + o;  o += (size_t)N * 4;
    float* scale1 = ws + o;  o += 128;
    float* shift1 = ws + o;  o += 128;
    float* scale2 = ws + o;  o += 128;
    float* shift2 = ws + o;  o += 128;
    // ---- zero region (one memset): bnsumA, bnsumB, gsum, gcnt, bSize ----
    size_t zoff = o;
    double* bnsumA = (double*)(ws + o); o += 512;
    double* bnsumB = (double*)(ws + o); o += 512;
    float* gsum   = ws + o;  o += 64 * 128;
    float* gcnt   = ws + o;  o += 64;
    int*   bSize  = (int*)(ws + o); o += 1024;
    size_t zbytes = (o - zoff) * 4;
    int* rowPtr   = (int*)(ws + o); o += (size_t)N + 1;
    int* sSrc     = (int*)(ws + o); o += E;
    int* bOff     = (int*)(ws + o); o += 1025;
    int* bCur     = (int*)(ws + o); o += 1024;
    unsigned int* bucketBuf = (unsigned int*)(ws + o); o += E;

    hipMemsetAsync(ws + zoff, 0, zbytes, stream);

    // ---- CSR build (bucket radix, shared by both layers) ----
    k_bhist<<<256, 256, 0, stream>>>(ei, bSize, E, nB);
    k_bscan<<<1, 512, 0, stream>>>(bSize, bOff, bCur, nB);
    k_part<<<256, 256, 0, stream>>>(ei, bCur, bucketBuf, E, nB);
    k_build<<<nB, 256, 0, stream>>>(bucketBuf, bOff, rowPtr, sSrc, N);

    int gemm_grid = (N + 63) / 64;
    int agg_grid = (N + 7) / 8;

    // ---- layer 1 ----
    k_gemm<16, false><<<gemm_grid, 256, 0, stream>>>(x, W1, nullptr, nullptr,
            att_s1, att_d1, hbuf, as_, ad_, N);
    k_agg<<<agg_grid, 256, 0, stream>>>(rowPtr, sSrc, as_, ad_, hbuf, outb, N);
    k_bnstats<<<1024, 256, 0, stream>>>(outb, bnsumA, N);
    k_bnscale<<<1, 128, 0, stream>>>(bnsumA, bn_g1, bn_b1, scale1, shift1, N);

    // ---- layer 2 ----
    k_gemm<128, true><<<gemm_grid, 256, 0, stream>>>(outb, W2, scale1, shift1,
            att_s2, att_d2, hbuf, as_, ad_, N);
    k_agg<<<agg_grid, 256, 0, stream>>>(rowPtr, sSrc, as_, ad_, hbuf, outb, N);
    k_bnstats<<<1024, 256, 0, stream>>>(outb, bnsumB, N);
    k_bnscale<<<1, 128, 0, stream>>>(bnsumB, bn_g2, bn_b2, scale2, shift2, N);

    // ---- pool + head ----
    k_pool<<<(N + 63) / 64, 128, 0, stream>>>(outb, batch, scale2, shift2, gsum, gcnt, N);
    k_head<<<1, 256, 0, stream>>>(gsum, gcnt, d1W, d1b, g_d1, b_d1,
                                  d2W, d2b, g_d2, b_d2, fcW, fcb, out);
}